// Round 3
// baseline (10103.828 us; speedup 1.0000x reference)
//
#include <hip/hip_runtime.h>

// ContinuousNormalizingFlow: B=32768 rows, D=8, H=64, 100 Euler steps.
// One thread per row. R3: all weights staged in LDS (broadcast ds_reads)
// to kill the scalar-K$ miss stalls seen in R2 (VALUBusy 22% of a 50% cap).

__device__ __forceinline__ float ftanh(float x) {
    // tanh(x) = 1 - 2/(exp(2x)+1); v_exp_f32 computes 2^x, inf-safe both ends.
    float e = __builtin_amdgcn_exp2f(x * 2.885390081777926815f); // 2*log2(e)
    float r = __builtin_amdgcn_rcpf(e + 1.0f);
    return fmaf(-2.0f, r, 1.0f);
}

__global__ __launch_bounds__(64) void cnf_kernel(
    const float* __restrict__ x0, const float* __restrict__ W1,
    const float* __restrict__ b1, const float* __restrict__ W2,
    const float* __restrict__ b2, const float* __restrict__ W3,
    const float* __restrict__ b3, const int* __restrict__ nsp,
    float* __restrict__ out, int rows) {
    // ---- LDS: weights (shared, broadcast-read) + per-lane dz2 spill ----
    __shared__ __align__(16) float sW2[64 * 64];   // row j contiguous in h (fwd) == row h contiguous in j (bwd)
    __shared__ __align__(16) float sW1x[64 * 8];   // W1[:, :8]
    __shared__ __align__(16) float sW3t[64 * 8];   // W3^T: [j][d]
    __shared__ __align__(16) float sbuf[64 * 64];  // dz2 per-lane column: sbuf[h*64+lane]
    __shared__ float sW1t[64], sb1[64], sb2[64], sw3c[64], sw1r[64], sb3[8];

    const int lane = threadIdx.x;
    const int row = blockIdx.x * 64 + lane;

    // ---- cooperative staging (64 threads) ----
    {
        const float4* src = (const float4*)W2;
        float4* dst = (float4*)sW2;
#pragma unroll
        for (int i = 0; i < 16; ++i) dst[lane + i * 64] = src[lane + i * 64];

        // W1 row `lane`: 9 floats; split x-part / t-part / bias; rowsum of x-part.
        float s = 0.f;
#pragma unroll
        for (int k = 0; k < 8; ++k) {
            float w = W1[lane * 9 + k];
            sW1x[lane * 8 + k] = w;
            s += w;
        }
        sw1r[lane] = s;
        sW1t[lane] = W1[lane * 9 + 8];
        sb1[lane] = b1[lane];
        sb2[lane] = b2[lane];

        // W3 column `lane` -> transpose + colsum.
        float c = 0.f;
#pragma unroll
        for (int d = 0; d < 8; ++d) {
            float w = W3[d * 64 + lane];
            sW3t[lane * 8 + d] = w;
            c += w;
        }
        sw3c[lane] = c;
        if (lane < 8) sb3[lane] = b3[lane];
    }
    __syncthreads();

    const int n = *nsp;
    const float dt = 1.0f / (float)n;

    float x[8];
    {
        const float4* p = (const float4*)(x0 + (size_t)row * 8);
        float4 a = p[0], b = p[1];
        x[0] = a.x; x[1] = a.y; x[2] = a.z; x[3] = a.w;
        x[4] = b.x; x[5] = b.y; x[6] = b.z; x[7] = b.w;
    }
    float ld = 0.f;

    for (int i = 0; i < n; ++i) {
        const float t = (float)i * dt;

        // ---------- forward layer 1 at x ----------
        float h1[64];
#pragma unroll
        for (int j = 0; j < 64; ++j) {
            const float* w = sW1x + j * 8;
            float a = fmaf(sW1t[j], t, sb1[j]);
#pragma unroll
            for (int k = 0; k < 8; ++k) a = fmaf(w[k], x[k], a);
            h1[j] = ftanh(a);
        }

        // ---------- layer 2 + 3 at x ----------
        float dx[8];
#pragma unroll
        for (int d = 0; d < 8; ++d) dx[d] = sb3[d];
#pragma unroll 4
        for (int j = 0; j < 64; ++j) {
            const float* w = sW2 + j * 64;
            float a0 = 0.f, a1 = 0.f, a2 = 0.f, a3 = 0.f;
#pragma unroll
            for (int h = 0; h < 64; h += 4) {
                a0 = fmaf(w[h + 0], h1[h + 0], a0);
                a1 = fmaf(w[h + 1], h1[h + 1], a1);
                a2 = fmaf(w[h + 2], h1[h + 2], a2);
                a3 = fmaf(w[h + 3], h1[h + 3], a3);
            }
            float h2 = ftanh(((a0 + a1) + (a2 + a3)) + sb2[j]);
            const float* w3t = sW3t + j * 8;
#pragma unroll
            for (int d = 0; d < 8; ++d) dx[d] = fmaf(w3t[d], h2, dx[d]);
        }
#pragma unroll
        for (int d = 0; d < 8; ++d) x[d] = fmaf(dt, dx[d], x[d]);

        // ---------- forward layer 1 at x_new (same t) ----------
        float h1p[64];
#pragma unroll
        for (int j = 0; j < 64; ++j) {
            const float* w = sW1x + j * 8;
            float a = fmaf(sW1t[j], t, sb1[j]);
#pragma unroll
            for (int k = 0; k < 8; ++k) a = fmaf(w[k], x[k], a);
            h1p[j] = ftanh(a);
        }

        // ---------- layer 2 at x_new -> dz2 = w3c*(1-h2'^2), spill to LDS ----------
#pragma unroll 4
        for (int j = 0; j < 64; ++j) {
            const float* w = sW2 + j * 64;
            float a0 = 0.f, a1 = 0.f, a2 = 0.f, a3 = 0.f;
#pragma unroll
            for (int h = 0; h < 64; h += 4) {
                a0 = fmaf(w[h + 0], h1p[h + 0], a0);
                a1 = fmaf(w[h + 1], h1p[h + 1], a1);
                a2 = fmaf(w[h + 2], h1p[h + 2], a2);
                a3 = fmaf(w[h + 3], h1p[h + 3], a3);
            }
            float th = ftanh(((a0 + a1) + (a2 + a3)) + sb2[j]);
            sbuf[j * 64 + lane] = sw3c[j] * fmaf(-th, th, 1.0f);
        }

        // ---------- dh1 = dz2 @ W2 (outer h rolled, inner j unrolled) ----------
        float dh1[64];
#pragma unroll
        for (int j = 0; j < 64; ++j) dh1[j] = 0.f;
#pragma unroll 2
        for (int h = 0; h < 64; ++h) {
            float v = sbuf[h * 64 + lane];
            const float* w = sW2 + h * 64;
#pragma unroll
            for (int j = 0; j < 64; ++j) dh1[j] = fmaf(w[j], v, dh1[j]);
        }

        // ---------- gsum = sum_j dh1[j]*(1-h1p[j]^2)*w1rowsum[j] ----------
        float g0 = 0.f, g1 = 0.f;
#pragma unroll
        for (int j = 0; j < 64; j += 2) {
            g0 = fmaf(dh1[j + 0] * fmaf(-h1p[j + 0], h1p[j + 0], 1.0f), sw1r[j + 0], g0);
            g1 = fmaf(dh1[j + 1] * fmaf(-h1p[j + 1], h1p[j + 1], 1.0f), sw1r[j + 1], g1);
        }
        ld = fmaf(dt, g0 + g1, ld);
    }

    // ---------- epilogue ----------
    float4* po = (float4*)(out + (size_t)row * 8);
    float4 o0, o1;
    o0.x = x[0]; o0.y = x[1]; o0.z = x[2]; o0.w = x[3];
    o1.x = x[4]; o1.y = x[5]; o1.z = x[6]; o1.w = x[7];
    po[0] = o0;
    po[1] = o1;
    out[(size_t)rows * 8 + row] = ld;
}

extern "C" void kernel_launch(void* const* d_in, const int* in_sizes, int n_in,
                              void* d_out, int out_size, void* d_ws, size_t ws_size,
                              hipStream_t stream) {
    const float* x0 = (const float*)d_in[0];
    const float* W1 = (const float*)d_in[1];
    const float* b1 = (const float*)d_in[2];
    const float* W2 = (const float*)d_in[3];
    const float* b2 = (const float*)d_in[4];
    const float* W3 = (const float*)d_in[5];
    const float* b3 = (const float*)d_in[6];
    const int* ns = (const int*)d_in[7];
    float* out = (float*)d_out;
    const int rows = in_sizes[0] / 8; // 32768

    hipLaunchKernelGGL(cnf_kernel, dim3(rows / 64), dim3(64), 0, stream,
                       x0, W1, b1, W2, b2, W3, b3, ns, out, rows);
}

// Round 4
// 3363.449 us; speedup vs baseline: 3.0040x; 3.0040x over previous
//
#include <hip/hip_runtime.h>

// ContinuousNormalizingFlow: B=32768 rows, D=8, H=64, 100 Euler steps.
// R4: split sequential forward (latency-bound, 512 waves) from the
// backward/log-det work (embarrassingly parallel over rows x steps).
// A: fwd-only chunk of S steps, trajectory -> d_ws. B: per (row,step)
// g-sum with wave-uniform SGPR weights, atomicAdd into ld.

__device__ float g_w1r[64];     // sum_{k<8} W1[j][k]
__device__ float g_w3c[64];     // sum_d W3[d][j]
__device__ float g_w3t[64 * 8]; // W3^T: [j][d]

__global__ void cnf_prep(const float* __restrict__ W1, const float* __restrict__ W3) {
    int h = threadIdx.x; // 64 threads
    float s = 0.f;
#pragma unroll
    for (int k = 0; k < 8; ++k) s += W1[h * 9 + k];
    g_w1r[h] = s;
    float c = 0.f;
#pragma unroll
    for (int d = 0; d < 8; ++d) {
        float w = W3[d * 64 + h];
        c += w;
        g_w3t[h * 8 + d] = w;
    }
    g_w3c[h] = c;
}

__device__ __forceinline__ float ftanh(float x) {
    // tanh(x) = 1 - 2/(exp(2x)+1); v_exp_f32 computes 2^x, inf-safe both ends.
    float e = __builtin_amdgcn_exp2f(x * 2.885390081777926815f); // 2*log2(e)
    float r = __builtin_amdgcn_rcpf(e + 1.0f);
    return fmaf(-2.0f, r, 1.0f);
}

// ---------------- Kernel A: sequential forward, S steps ----------------
__global__ __launch_bounds__(64) void cnf_fwd(
    const float* __restrict__ x0, const float* __restrict__ W1,
    const float* __restrict__ b1, const float* __restrict__ W2,
    const float* __restrict__ b2, const float* __restrict__ b3,
    const int* __restrict__ nsp, float* __restrict__ xstate,
    float* __restrict__ traj, float* __restrict__ out,
    int rows, int i0, int S, int last) {
    const int lane = threadIdx.x;
    const int row = blockIdx.x * 64 + lane;
    const int n = *nsp;
    const float dt = 1.0f / (float)n;

    float x[8];
    {
        const float* src = (i0 == 0) ? x0 : xstate;
        const float4* p = (const float4*)(src + (size_t)row * 8);
        float4 a = p[0], b = p[1];
        x[0] = a.x; x[1] = a.y; x[2] = a.z; x[3] = a.w;
        x[4] = b.x; x[5] = b.y; x[6] = b.z; x[7] = b.w;
    }

    for (int s = 0; s < S; ++s) {
        const int i = i0 + s;
        if (i >= n) break;
        const float t = (float)i * dt;

        float h1[64];
#pragma unroll
        for (int j = 0; j < 64; ++j) {
            const float* w = W1 + j * 9;
            float a = fmaf(w[8], t, b1[j]);
#pragma unroll
            for (int k = 0; k < 8; ++k) a = fmaf(w[k], x[k], a);
            h1[j] = ftanh(a);
        }

        float dx[8];
#pragma unroll
        for (int d = 0; d < 8; ++d) dx[d] = b3[d];
#pragma unroll 4
        for (int j = 0; j < 64; ++j) {
            const float* w = W2 + j * 64;
            float a0 = 0.f, a1 = 0.f, a2 = 0.f, a3 = 0.f;
#pragma unroll
            for (int h = 0; h < 64; h += 4) {
                a0 = fmaf(w[h + 0], h1[h + 0], a0);
                a1 = fmaf(w[h + 1], h1[h + 1], a1);
                a2 = fmaf(w[h + 2], h1[h + 2], a2);
                a3 = fmaf(w[h + 3], h1[h + 3], a3);
            }
            float h2 = ftanh(((a0 + a1) + (a2 + a3)) + b2[j]);
            const float* w3t = g_w3t + j * 8;
#pragma unroll
            for (int d = 0; d < 8; ++d) dx[d] = fmaf(w3t[d], h2, dx[d]);
        }
#pragma unroll
        for (int d = 0; d < 8; ++d) x[d] = fmaf(dt, dx[d], x[d]);

        // store post-step x (x_{i+1}) for kernel B
        float4* tp = (float4*)(traj + ((size_t)s * rows + row) * 8);
        float4 o0, o1;
        o0.x = x[0]; o0.y = x[1]; o0.z = x[2]; o0.w = x[3];
        o1.x = x[4]; o1.y = x[5]; o1.z = x[6]; o1.w = x[7];
        tp[0] = o0; tp[1] = o1;
    }

    float4* xs = (float4*)(xstate + (size_t)row * 8);
    float4 o0, o1;
    o0.x = x[0]; o0.y = x[1]; o0.z = x[2]; o0.w = x[3];
    o1.x = x[4]; o1.y = x[5]; o1.z = x[6]; o1.w = x[7];
    xs[0] = o0; xs[1] = o1;
    if (last) {
        float4* po = (float4*)(out + (size_t)row * 8);
        po[0] = o0; po[1] = o1;
    }
}

// ------------- Kernel B: per (row, step) log-det contribution -------------
// gsum = sum_j dz2[j] * (sum_h W2[j][h]*u[h]);  u[h]=(1-h1p[h]^2)*w1r[h]
// dz2[j] = w3c[j]*(1-h2p[j]^2). Both dots share each W2 row's s_loads.
__global__ __launch_bounds__(256) void cnf_bwd(
    const float* __restrict__ W1, const float* __restrict__ b1,
    const float* __restrict__ W2, const float* __restrict__ b2,
    const int* __restrict__ nsp, const float* __restrict__ traj,
    float* __restrict__ ld, int rows, int i0, int S) {
    const int n = *nsp;
    const float dt = 1.0f / (float)n;
    const int lane = threadIdx.x & 63;
    const int task = blockIdx.x * 4 + (threadIdx.x >> 6); // wave-task
    const int nrb = rows / 64;                            // 512
    const int rowblk = task % nrb;
    const int s = task / nrb;
    const int i = i0 + s;
    if (i >= n) return;
    const int row = rowblk * 64 + lane;
    const float t = (float)i * dt;

    float x[8];
    {
        const float4* p = (const float4*)(traj + ((size_t)s * rows + row) * 8);
        float4 a = p[0], b = p[1];
        x[0] = a.x; x[1] = a.y; x[2] = a.z; x[3] = a.w;
        x[4] = b.x; x[5] = b.y; x[6] = b.z; x[7] = b.w;
    }

    float h1p[64], u[64];
#pragma unroll
    for (int j = 0; j < 64; ++j) {
        const float* w = W1 + j * 9;
        float a = fmaf(w[8], t, b1[j]);
#pragma unroll
        for (int k = 0; k < 8; ++k) a = fmaf(w[k], x[k], a);
        float th = ftanh(a);
        h1p[j] = th;
        u[j] = fmaf(-th, th, 1.0f) * g_w1r[j];
    }

    float gs0 = 0.f, gs1 = 0.f;
#pragma unroll 2
    for (int j = 0; j < 64; ++j) {
        const float* w = W2 + j * 64;
        float a0 = 0.f, a1 = 0.f, s0 = 0.f, s1 = 0.f;
#pragma unroll
        for (int h = 0; h < 64; h += 2) {
            float w0 = w[h], w1 = w[h + 1];
            a0 = fmaf(w0, h1p[h], a0);
            a1 = fmaf(w1, h1p[h + 1], a1);
            s0 = fmaf(w0, u[h], s0);
            s1 = fmaf(w1, u[h + 1], s1);
        }
        float th2 = ftanh((a0 + a1) + b2[j]);
        float dz2 = g_w3c[j] * fmaf(-th2, th2, 1.0f);
        if (j & 1) gs1 = fmaf(dz2, s0 + s1, gs1);
        else       gs0 = fmaf(dz2, s0 + s1, gs0);
    }
    atomicAdd(&ld[row], dt * (gs0 + gs1));
}

// ------------- Fallback: R2 monolith (used only if ws too small) -------------
__global__ __launch_bounds__(64) void cnf_mono(
    const float* __restrict__ x0, const float* __restrict__ W1,
    const float* __restrict__ b1, const float* __restrict__ W2,
    const float* __restrict__ b2, const float* __restrict__ b3,
    const int* __restrict__ nsp, float* __restrict__ out, int rows) {
    const int lane = threadIdx.x;
    const int row = blockIdx.x * 64 + lane;
    const int n = *nsp;
    const float dt = 1.0f / (float)n;
    float x[8];
    {
        const float4* p = (const float4*)(x0 + (size_t)row * 8);
        float4 a = p[0], b = p[1];
        x[0] = a.x; x[1] = a.y; x[2] = a.z; x[3] = a.w;
        x[4] = b.x; x[5] = b.y; x[6] = b.z; x[7] = b.w;
    }
    float ld = 0.f;
    for (int i = 0; i < n; ++i) {
        const float t = (float)i * dt;
        float h1[64];
#pragma unroll
        for (int j = 0; j < 64; ++j) {
            const float* w = W1 + j * 9;
            float a = fmaf(w[8], t, b1[j]);
#pragma unroll
            for (int k = 0; k < 8; ++k) a = fmaf(w[k], x[k], a);
            h1[j] = ftanh(a);
        }
        float dx[8];
#pragma unroll
        for (int d = 0; d < 8; ++d) dx[d] = b3[d];
#pragma unroll 4
        for (int j = 0; j < 64; ++j) {
            const float* w = W2 + j * 64;
            float a0 = 0.f, a1 = 0.f, a2 = 0.f, a3 = 0.f;
#pragma unroll
            for (int h = 0; h < 64; h += 4) {
                a0 = fmaf(w[h], h1[h], a0);
                a1 = fmaf(w[h + 1], h1[h + 1], a1);
                a2 = fmaf(w[h + 2], h1[h + 2], a2);
                a3 = fmaf(w[h + 3], h1[h + 3], a3);
            }
            float h2 = ftanh(((a0 + a1) + (a2 + a3)) + b2[j]);
            const float* w3t = g_w3t + j * 8;
#pragma unroll
            for (int d = 0; d < 8; ++d) dx[d] = fmaf(w3t[d], h2, dx[d]);
        }
#pragma unroll
        for (int d = 0; d < 8; ++d) x[d] = fmaf(dt, dx[d], x[d]);
        float h1p[64], uu[64];
#pragma unroll
        for (int j = 0; j < 64; ++j) {
            const float* w = W1 + j * 9;
            float a = fmaf(w[8], t, b1[j]);
#pragma unroll
            for (int k = 0; k < 8; ++k) a = fmaf(w[k], x[k], a);
            float th = ftanh(a);
            h1p[j] = th;
            uu[j] = fmaf(-th, th, 1.0f) * g_w1r[j];
        }
        float gs = 0.f;
#pragma unroll 2
        for (int j = 0; j < 64; ++j) {
            const float* w = W2 + j * 64;
            float a0 = 0.f, a1 = 0.f, s0 = 0.f, s1 = 0.f;
#pragma unroll
            for (int h = 0; h < 64; h += 2) {
                float w0 = w[h], w1 = w[h + 1];
                a0 = fmaf(w0, h1p[h], a0);
                a1 = fmaf(w1, h1p[h + 1], a1);
                s0 = fmaf(w0, uu[h], s0);
                s1 = fmaf(w1, uu[h + 1], s1);
            }
            float th2 = ftanh((a0 + a1) + b2[j]);
            float dz2 = g_w3c[j] * fmaf(-th2, th2, 1.0f);
            gs = fmaf(dz2, s0 + s1, gs);
        }
        ld = fmaf(dt, gs, ld);
    }
    float4* po = (float4*)(out + (size_t)row * 8);
    float4 o0, o1;
    o0.x = x[0]; o0.y = x[1]; o0.z = x[2]; o0.w = x[3];
    o1.x = x[4]; o1.y = x[5]; o1.z = x[6]; o1.w = x[7];
    po[0] = o0; po[1] = o1;
    out[(size_t)rows * 8 + row] = ld;
}

extern "C" void kernel_launch(void* const* d_in, const int* in_sizes, int n_in,
                              void* d_out, int out_size, void* d_ws, size_t ws_size,
                              hipStream_t stream) {
    const float* x0 = (const float*)d_in[0];
    const float* W1 = (const float*)d_in[1];
    const float* b1 = (const float*)d_in[2];
    const float* W2 = (const float*)d_in[3];
    const float* b2 = (const float*)d_in[4];
    const float* W3 = (const float*)d_in[5];
    const float* b3 = (const float*)d_in[6];
    const int* ns = (const int*)d_in[7];
    float* out = (float*)d_out;
    const int rows = in_sizes[0] / 8; // 32768
    const int TOT = 100;              // reference STEPS (device n also guards)

    hipLaunchKernelGGL(cnf_prep, dim3(1), dim3(64), 0, stream, W1, W3);

    const size_t xs_bytes = (size_t)rows * 8 * 4;
    const size_t step_bytes = (size_t)rows * 8 * 4;
    int S = 10;
    while (S > 1 && xs_bytes + (size_t)S * step_bytes > ws_size) --S;

    if (xs_bytes + (size_t)S * step_bytes > ws_size) {
        // workspace too small: monolithic fallback
        hipLaunchKernelGGL(cnf_mono, dim3(rows / 64), dim3(64), 0, stream,
                           x0, W1, b1, W2, b2, b3, ns, out, rows);
        return;
    }

    float* xstate = (float*)d_ws;
    float* traj = (float*)((char*)d_ws + xs_bytes);
    float* ldp = out + (size_t)rows * 8;

    hipMemsetAsync(ldp, 0, (size_t)rows * 4, stream);

    const int nch = (TOT + S - 1) / S;
    for (int c = 0; c < nch; ++c) {
        const int i0 = c * S;
        const int last = (c == nch - 1) ? 1 : 0;
        hipLaunchKernelGGL(cnf_fwd, dim3(rows / 64), dim3(64), 0, stream,
                           x0, W1, b1, W2, b2, b3, ns, xstate, traj, out,
                           rows, i0, S, last);
        const int tasks = (rows / 64) * S;            // wave-tasks this chunk
        hipLaunchKernelGGL(cnf_bwd, dim3((tasks + 3) / 4), dim3(256), 0, stream,
                           W1, b1, W2, b2, ns, traj, ldp, rows, i0, S);
    }
}

// Round 6
// 920.696 us; speedup vs baseline: 10.9741x; 3.6532x over previous
//
#include <hip/hip_runtime.h>

// ContinuousNormalizingFlow: B=32768 rows, D=8, H=64, 100 Euler steps.
// R6: fwd via bf16 MFMA, transposed (h^T = W @ x^T) so W1/W2/W3 are
// persistent A-frags in VGPRs (zero weight loads in the step loop — kills
// the scalar-K$ latency that capped R4 fwd at VALUBusy 10.7%).
// bwd: unchanged fp32 thread-per-(row,step) kernel (near its VALU ceiling).

__device__ float g_w1r[64];     // sum_{k<8} W1[j][k]
__device__ float g_w3c[64];     // sum_d W3[d][j]
__device__ float g_w3t[64 * 8]; // W3^T: [j][d] (mono fallback only)

__global__ void cnf_prep(const float* __restrict__ W1, const float* __restrict__ W3) {
    int h = threadIdx.x; // 64 threads
    float s = 0.f;
#pragma unroll
    for (int k = 0; k < 8; ++k) s += W1[h * 9 + k];
    g_w1r[h] = s;
    float c = 0.f;
#pragma unroll
    for (int d = 0; d < 8; ++d) {
        float w = W3[d * 64 + h];
        c += w;
        g_w3t[h * 8 + d] = w;
    }
    g_w3c[h] = c;
}

__device__ __forceinline__ float ftanh(float x) {
    // tanh(x) = 1 - 2/(exp(2x)+1); v_exp_f32 computes 2^x, inf-safe both ends.
    float e = __builtin_amdgcn_exp2f(x * 2.885390081777926815f); // 2*log2(e)
    float r = __builtin_amdgcn_rcpf(e + 1.0f);
    return fmaf(-2.0f, r, 1.0f);
}

typedef __attribute__((ext_vector_type(8))) short v8s; // 8 bf16 (4 VGPRs)
typedef __attribute__((ext_vector_type(4))) float v4f; // MFMA C/D

union FragU {
    v8s s;
    unsigned u[4];
};

__device__ __forceinline__ unsigned bf16r(float f) {
    // round-to-nearest-even bf16, as bits in low 16
    unsigned u = __builtin_bit_cast(unsigned, f);
    u += 0x7fffu + ((u >> 16) & 1u);
    return u >> 16;
}
__device__ __forceinline__ unsigned pkbf(float a, float b) {
    return bf16r(a) | (bf16r(b) << 16); // a -> low half
}

// ---------------- Kernel A: sequential forward via MFMA ----------------
// Wave handles 16 batch rows (N dim). mfma_f32_16x16x32_bf16 layouts:
//   A[m=lane&15][k=(lane>>4)*8+j], B[k=(lane>>4)*8+j][n=lane&15],
//   C/D[row=(lane>>4)*4+reg][col=lane&15].
__global__ __launch_bounds__(256) void cnf_fwd_mfma(
    const float* __restrict__ x0, const float* __restrict__ W1,
    const float* __restrict__ b1, const float* __restrict__ W2,
    const float* __restrict__ b2, const float* __restrict__ W3,
    const float* __restrict__ b3, const int* __restrict__ nsp,
    float* __restrict__ xstate, float* __restrict__ traj,
    float* __restrict__ out, int rows, int i0, int S, int last) {
    // per-wave LDS; stride 72 shorts (144 B) per batch row -> 2-way banks only
    __shared__ short hbuf[4][16 * 72];
    __shared__ short xbuf[4][16 * 8];
    const int tid = threadIdx.x;
    const int w = tid >> 6;
    const int lane = tid & 63;
    const int c = lane & 15;  // batch row within wave-tile / A-row m
    const int q = lane >> 4;  // k-chunk quad
    const int row0 = blockIdx.x * 64 + w * 16;
    short* hb = hbuf[w];
    short* xb = xbuf[w];

    const int n = *nsp;
    const float dt = 1.0f / (float)n;

    // ---- persistent A-frags (weights, bf16) ----
    FragU a1[4]; // W1 [64x9], k==9 carries b1 (bias trick; B1[9][*]=1)
#pragma unroll
    for (int mt = 0; mt < 4; ++mt) {
        const int m = 16 * mt + c;
        float f[8];
#pragma unroll
        for (int jj = 0; jj < 8; ++jj) {
            const int k = 8 * q + jj;
            f[jj] = (k < 9) ? W1[m * 9 + k] : ((k == 9) ? b1[m] : 0.f);
        }
#pragma unroll
        for (int p = 0; p < 4; ++p) a1[mt].u[p] = pkbf(f[2 * p], f[2 * p + 1]);
    }
    FragU a2[4][2]; // W2 [64x64]
#pragma unroll
    for (int mt = 0; mt < 4; ++mt)
#pragma unroll
        for (int ks = 0; ks < 2; ++ks) {
            const int m = 16 * mt + c;
            float f[8];
#pragma unroll
            for (int jj = 0; jj < 8; ++jj) f[jj] = W2[m * 64 + 32 * ks + 8 * q + jj];
#pragma unroll
            for (int p = 0; p < 4; ++p) a2[mt][ks].u[p] = pkbf(f[2 * p], f[2 * p + 1]);
        }
    FragU a3[2]; // W3 [8x64], rows 8..15 zero
#pragma unroll
    for (int ks = 0; ks < 2; ++ks) {
        float f[8];
#pragma unroll
        for (int jj = 0; jj < 8; ++jj)
            f[jj] = (c < 8) ? W3[c * 64 + 32 * ks + 8 * q + jj] : 0.f;
#pragma unroll
        for (int p = 0; p < 4; ++p) a3[ks].u[p] = pkbf(f[2 * p], f[2 * p + 1]);
    }
    float b2v[4][4];
#pragma unroll
    for (int mt = 0; mt < 4; ++mt)
#pragma unroll
        for (int r = 0; r < 4; ++r) b2v[mt][r] = b2[16 * mt + 4 * q + r];
    float b3v[4];
#pragma unroll
    for (int r = 0; r < 4; ++r) b3v[r] = (q < 2) ? b3[4 * q + r] : 0.f;

    // ---- x state: lanes q in {0,1} hold x[row0+c][4q+r], fp32 master ----
    float xr[4] = {0.f, 0.f, 0.f, 0.f};
    {
        const float* src = (i0 == 0) ? x0 : xstate;
        if (q < 2) {
            float4 v = *(const float4*)(src + (size_t)(row0 + c) * 8 + 4 * q);
            xr[0] = v.x; xr[1] = v.y; xr[2] = v.z; xr[3] = v.w;
        }
    }
    const v4f vzero = {0.f, 0.f, 0.f, 0.f};

    for (int s = 0; s < S; ++s) {
        const int i = i0 + s;
        if (i >= n) break;
        const float t = (float)i * dt;

        // ---- B1 frag: xt^T (x rows as bf16 via xbuf; k=8 -> t, k=9 -> 1) ----
        if (q < 2) {
            uint2 pw;
            pw.x = pkbf(xr[0], xr[1]);
            pw.y = pkbf(xr[2], xr[3]);
            *(uint2*)&xb[c * 8 + 4 * q] = pw;
        }
        FragU bf1;
        bf1.u[0] = bf1.u[1] = bf1.u[2] = bf1.u[3] = 0u;
        if (q == 0) {
            bf1.s = *(const v8s*)&xb[c * 8];
        } else if (q == 1) {
            bf1.u[0] = pkbf(t, 1.0f); // k=8: t, k=9: 1 (bias row)
        }

        // ---- L1: h1^T = W1 @ xt^T ----
        v4f d1[4];
#pragma unroll
        for (int mt = 0; mt < 4; ++mt)
            d1[mt] = __builtin_amdgcn_mfma_f32_16x16x32_bf16(a1[mt].s, bf1.s, vzero, 0, 0, 0);

        // tanh + pack to hbuf [c][j] bf16
#pragma unroll
        for (int mt = 0; mt < 4; ++mt) {
            float t0 = ftanh(d1[mt][0]), t1 = ftanh(d1[mt][1]);
            float t2 = ftanh(d1[mt][2]), t3 = ftanh(d1[mt][3]);
            uint2 pw;
            pw.x = pkbf(t0, t1);
            pw.y = pkbf(t2, t3);
            *(uint2*)&hb[c * 72 + 16 * mt + 4 * q] = pw;
        }
        FragU bf2[2];
#pragma unroll
        for (int ks = 0; ks < 2; ++ks) bf2[ks].s = *(const v8s*)&hb[c * 72 + 32 * ks + 8 * q];

        // ---- L2: h2^T = W2 @ h1^T ----
        v4f d2[4];
#pragma unroll
        for (int mt = 0; mt < 4; ++mt) {
            d2[mt] = __builtin_amdgcn_mfma_f32_16x16x32_bf16(a2[mt][0].s, bf2[0].s, vzero, 0, 0, 0);
            d2[mt] = __builtin_amdgcn_mfma_f32_16x16x32_bf16(a2[mt][1].s, bf2[1].s, d2[mt], 0, 0, 0);
        }
#pragma unroll
        for (int mt = 0; mt < 4; ++mt) {
            float t0 = ftanh(d2[mt][0] + b2v[mt][0]), t1 = ftanh(d2[mt][1] + b2v[mt][1]);
            float t2 = ftanh(d2[mt][2] + b2v[mt][2]), t3 = ftanh(d2[mt][3] + b2v[mt][3]);
            uint2 pw;
            pw.x = pkbf(t0, t1);
            pw.y = pkbf(t2, t3);
            *(uint2*)&hb[c * 72 + 16 * mt + 4 * q] = pw;
        }
        FragU bf3[2];
#pragma unroll
        for (int ks = 0; ks < 2; ++ks) bf3[ks].s = *(const v8s*)&hb[c * 72 + 32 * ks + 8 * q];

        // ---- L3: dx^T = W3 @ h2^T (rows 8..15 zero) ----
        v4f d3;
        d3 = __builtin_amdgcn_mfma_f32_16x16x32_bf16(a3[0].s, bf3[0].s, vzero, 0, 0, 0);
        d3 = __builtin_amdgcn_mfma_f32_16x16x32_bf16(a3[1].s, bf3[1].s, d3, 0, 0, 0);

        // ---- Euler update (C-layout matches x ownership) + traj store ----
        if (q < 2) {
#pragma unroll
            for (int r = 0; r < 4; ++r) xr[r] = fmaf(dt, d3[r] + b3v[r], xr[r]);
            float4 st = {xr[0], xr[1], xr[2], xr[3]};
            *(float4*)(traj + ((size_t)s * rows + row0 + c) * 8 + 4 * q) = st;
        }
    }

    if (q < 2) {
        float4 st = {xr[0], xr[1], xr[2], xr[3]};
        *(float4*)(xstate + (size_t)(row0 + c) * 8 + 4 * q) = st;
        if (last) *(float4*)(out + (size_t)(row0 + c) * 8 + 4 * q) = st;
    }
}

// ------------- Kernel B: per (row, step) log-det contribution -------------
__global__ __launch_bounds__(256) void cnf_bwd(
    const float* __restrict__ W1, const float* __restrict__ b1,
    const float* __restrict__ W2, const float* __restrict__ b2,
    const int* __restrict__ nsp, const float* __restrict__ traj,
    float* __restrict__ ld, int rows, int i0, int S) {
    const int n = *nsp;
    const float dt = 1.0f / (float)n;
    const int lane = threadIdx.x & 63;
    const int task = blockIdx.x * 4 + (threadIdx.x >> 6); // wave-task
    const int nrb = rows / 64;                            // 512
    const int rowblk = task % nrb;
    const int s = task / nrb;
    const int i = i0 + s;
    if (i >= n) return;
    const int row = rowblk * 64 + lane;
    const float t = (float)i * dt;

    float x[8];
    {
        const float4* p = (const float4*)(traj + ((size_t)s * rows + row) * 8);
        float4 a = p[0], b = p[1];
        x[0] = a.x; x[1] = a.y; x[2] = a.z; x[3] = a.w;
        x[4] = b.x; x[5] = b.y; x[6] = b.z; x[7] = b.w;
    }

    float h1p[64], u[64];
#pragma unroll
    for (int j = 0; j < 64; ++j) {
        const float* w = W1 + j * 9;
        float a = fmaf(w[8], t, b1[j]);
#pragma unroll
        for (int k = 0; k < 8; ++k) a = fmaf(w[k], x[k], a);
        float th = ftanh(a);
        h1p[j] = th;
        u[j] = fmaf(-th, th, 1.0f) * g_w1r[j];
    }

    float gs0 = 0.f, gs1 = 0.f;
#pragma unroll 2
    for (int j = 0; j < 64; ++j) {
        const float* w = W2 + j * 64;
        float a0 = 0.f, a1 = 0.f, s0 = 0.f, s1 = 0.f;
#pragma unroll
        for (int h = 0; h < 64; h += 2) {
            float w0 = w[h], w1 = w[h + 1];
            a0 = fmaf(w0, h1p[h], a0);
            a1 = fmaf(w1, h1p[h + 1], a1);
            s0 = fmaf(w0, u[h], s0);
            s1 = fmaf(w1, u[h + 1], s1);
        }
        float th2 = ftanh((a0 + a1) + b2[j]);
        float dz2 = g_w3c[j] * fmaf(-th2, th2, 1.0f);
        if (j & 1) gs1 = fmaf(dz2, s0 + s1, gs1);
        else       gs0 = fmaf(dz2, s0 + s1, gs0);
    }
    atomicAdd(&ld[row], dt * (gs0 + gs1));
}

// ------------- Fallback: R2 monolith (used only if ws too small) -------------
__global__ __launch_bounds__(64) void cnf_mono(
    const float* __restrict__ x0, const float* __restrict__ W1,
    const float* __restrict__ b1, const float* __restrict__ W2,
    const float* __restrict__ b2, const float* __restrict__ b3,
    const int* __restrict__ nsp, float* __restrict__ out, int rows) {
    const int lane = threadIdx.x;
    const int row = blockIdx.x * 64 + lane;
    const int n = *nsp;
    const float dt = 1.0f / (float)n;
    float x[8];
    {
        const float4* p = (const float4*)(x0 + (size_t)row * 8);
        float4 a = p[0], b = p[1];
        x[0] = a.x; x[1] = a.y; x[2] = a.z; x[3] = a.w;
        x[4] = b.x; x[5] = b.y; x[6] = b.z; x[7] = b.w;
    }
    float ld = 0.f;
    for (int i = 0; i < n; ++i) {
        const float t = (float)i * dt;
        float h1[64];
#pragma unroll
        for (int j = 0; j < 64; ++j) {
            const float* w = W1 + j * 9;
            float a = fmaf(w[8], t, b1[j]);
#pragma unroll
            for (int k = 0; k < 8; ++k) a = fmaf(w[k], x[k], a);
            h1[j] = ftanh(a);
        }
        float dx[8];
#pragma unroll
        for (int d = 0; d < 8; ++d) dx[d] = b3[d];
#pragma unroll 4
        for (int j = 0; j < 64; ++j) {
            const float* w = W2 + j * 64;
            float a0 = 0.f, a1 = 0.f, a2 = 0.f, a3 = 0.f;
#pragma unroll
            for (int h = 0; h < 64; h += 4) {
                a0 = fmaf(w[h], h1[h], a0);
                a1 = fmaf(w[h + 1], h1[h + 1], a1);
                a2 = fmaf(w[h + 2], h1[h + 2], a2);
                a3 = fmaf(w[h + 3], h1[h + 3], a3);
            }
            float h2 = ftanh(((a0 + a1) + (a2 + a3)) + b2[j]);
            const float* w3t = g_w3t + j * 8;
#pragma unroll
            for (int d = 0; d < 8; ++d) dx[d] = fmaf(w3t[d], h2, dx[d]);
        }
#pragma unroll
        for (int d = 0; d < 8; ++d) x[d] = fmaf(dt, dx[d], x[d]);
        float h1p[64], uu[64];
#pragma unroll
        for (int j = 0; j < 64; ++j) {
            const float* w = W1 + j * 9;
            float a = fmaf(w[8], t, b1[j]);
#pragma unroll
            for (int k = 0; k < 8; ++k) a = fmaf(w[k], x[k], a);
            float th = ftanh(a);
            h1p[j] = th;
            uu[j] = fmaf(-th, th, 1.0f) * g_w1r[j];
        }
        float gs = 0.f;
#pragma unroll 2
        for (int j = 0; j < 64; ++j) {
            const float* w = W2 + j * 64;
            float a0 = 0.f, a1 = 0.f, s0 = 0.f, s1 = 0.f;
#pragma unroll
            for (int h = 0; h < 64; h += 2) {
                float w0 = w[h], w1 = w[h + 1];
                a0 = fmaf(w0, h1p[h], a0);
                a1 = fmaf(w1, h1p[h + 1], a1);
                s0 = fmaf(w0, uu[h], s0);
                s1 = fmaf(w1, uu[h + 1], s1);
            }
            float th2 = ftanh((a0 + a1) + b2[j]);
            float dz2 = g_w3c[j] * fmaf(-th2, th2, 1.0f);
            gs = fmaf(dz2, s0 + s1, gs);
        }
        ld = fmaf(dt, gs, ld);
    }
    float4* po = (float4*)(out + (size_t)row * 8);
    float4 o0, o1;
    o0.x = x[0]; o0.y = x[1]; o0.z = x[2]; o0.w = x[3];
    o1.x = x[4]; o1.y = x[5]; o1.z = x[6]; o1.w = x[7];
    po[0] = o0; po[1] = o1;
    out[(size_t)rows * 8 + row] = ld;
}

extern "C" void kernel_launch(void* const* d_in, const int* in_sizes, int n_in,
                              void* d_out, int out_size, void* d_ws, size_t ws_size,
                              hipStream_t stream) {
    const float* x0 = (const float*)d_in[0];
    const float* W1 = (const float*)d_in[1];
    const float* b1 = (const float*)d_in[2];
    const float* W2 = (const float*)d_in[3];
    const float* b2 = (const float*)d_in[4];
    const float* W3 = (const float*)d_in[5];
    const float* b3 = (const float*)d_in[6];
    const int* ns = (const int*)d_in[7];
    float* out = (float*)d_out;
    const int rows = in_sizes[0] / 8; // 32768
    const int TOT = 100;              // reference STEPS (device n also guards)

    hipLaunchKernelGGL(cnf_prep, dim3(1), dim3(64), 0, stream, W1, W3);

    const size_t xs_bytes = (size_t)rows * 8 * 4;
    const size_t step_bytes = (size_t)rows * 8 * 4;
    int S = 10;
    while (S > 1 && xs_bytes + (size_t)S * step_bytes > ws_size) --S;

    if (xs_bytes + (size_t)S * step_bytes > ws_size) {
        hipLaunchKernelGGL(cnf_mono, dim3(rows / 64), dim3(64), 0, stream,
                           x0, W1, b1, W2, b2, b3, ns, out, rows);
        return;
    }

    float* xstate = (float*)d_ws;
    float* traj = (float*)((char*)d_ws + xs_bytes);
    float* ldp = out + (size_t)rows * 8;

    (void)hipMemsetAsync(ldp, 0, (size_t)rows * 4, stream);

    const int nch = (TOT + S - 1) / S;
    for (int c = 0; c < nch; ++c) {
        const int i0 = c * S;
        const int last = (c == nch - 1) ? 1 : 0;
        hipLaunchKernelGGL(cnf_fwd_mfma, dim3(rows / 64), dim3(256), 0, stream,
                           x0, W1, b1, W2, b2, W3, b3, ns, xstate, traj, out,
                           rows, i0, S, last);
        const int tasks = (rows / 64) * S; // wave-tasks this chunk
        hipLaunchKernelGGL(cnf_bwd, dim3((tasks + 3) / 4), dim3(256), 0, stream,
                           W1, b1, W2, b2, ns, traj, ldp, rows, i0, S);
    }
}

// Round 7
// 526.891 us; speedup vs baseline: 19.1763x; 1.7474x over previous
//
#include <hip/hip_runtime.h>

// ContinuousNormalizingFlow: B=32768 rows, D=8, H=64, 100 Euler steps.
// R7: both fwd and bwd via bf16 MFMA with persistent weight A-frags.
// fwd: sequential over steps, 16 rows/wave (2048 waves).
// bwd: parallel over (16-row tile, step), KSTEP steps/wave to amortize
//      frag setup; g accumulated in-register, one atomic per wave per row.

#define KSTEP 5

__device__ float g_w1r[64];     // sum_{k<8} W1[j][k]
__device__ float g_w3c[64];     // sum_d W3[d][j]
__device__ float g_w3t[64 * 8]; // W3^T: [j][d] (mono fallback only)

__global__ void cnf_prep(const float* __restrict__ W1, const float* __restrict__ W3) {
    int h = threadIdx.x; // 64 threads
    float s = 0.f;
#pragma unroll
    for (int k = 0; k < 8; ++k) s += W1[h * 9 + k];
    g_w1r[h] = s;
    float c = 0.f;
#pragma unroll
    for (int d = 0; d < 8; ++d) {
        float w = W3[d * 64 + h];
        c += w;
        g_w3t[h * 8 + d] = w;
    }
    g_w3c[h] = c;
}

__device__ __forceinline__ float ftanh(float x) {
    // tanh(x) = 1 - 2/(exp(2x)+1); v_exp_f32 computes 2^x, inf-safe both ends.
    float e = __builtin_amdgcn_exp2f(x * 2.885390081777926815f); // 2*log2(e)
    float r = __builtin_amdgcn_rcpf(e + 1.0f);
    return fmaf(-2.0f, r, 1.0f);
}

typedef __attribute__((ext_vector_type(8))) short v8s; // 8 bf16 (4 VGPRs)
typedef __attribute__((ext_vector_type(4))) float v4f; // MFMA C/D

union FragU {
    v8s s;
    unsigned u[4];
};

__device__ __forceinline__ unsigned bf16r(float f) {
    unsigned u = __builtin_bit_cast(unsigned, f);
    u += 0x7fffu + ((u >> 16) & 1u);
    return u >> 16;
}
__device__ __forceinline__ unsigned pkbf(float a, float b) {
    return bf16r(a) | (bf16r(b) << 16); // a -> low half
}

// ---- shared frag-builders (mfma_f32_16x16x32_bf16 layouts):
//   A[m=lane&15][k=(lane>>4)*8+j], B[k=(lane>>4)*8+j][n=lane&15],
//   C/D[row=(lane>>4)*4+reg][col=lane&15].
__device__ __forceinline__ void load_a1(FragU a1[4], const float* W1,
                                        const float* b1, int c, int q) {
#pragma unroll
    for (int mt = 0; mt < 4; ++mt) {
        const int m = 16 * mt + c;
        float f[8];
#pragma unroll
        for (int jj = 0; jj < 8; ++jj) {
            const int k = 8 * q + jj;
            f[jj] = (k < 9) ? W1[m * 9 + k] : ((k == 9) ? b1[m] : 0.f);
        }
#pragma unroll
        for (int p = 0; p < 4; ++p) a1[mt].u[p] = pkbf(f[2 * p], f[2 * p + 1]);
    }
}
__device__ __forceinline__ void load_a2(FragU a2[4][2], const float* W2,
                                        int c, int q) {
#pragma unroll
    for (int mt = 0; mt < 4; ++mt)
#pragma unroll
        for (int ks = 0; ks < 2; ++ks) {
            const int m = 16 * mt + c;
            float f[8];
#pragma unroll
            for (int jj = 0; jj < 8; ++jj) f[jj] = W2[m * 64 + 32 * ks + 8 * q + jj];
#pragma unroll
            for (int p = 0; p < 4; ++p) a2[mt][ks].u[p] = pkbf(f[2 * p], f[2 * p + 1]);
        }
}

// ---------------- Kernel A: sequential forward via MFMA ----------------
__global__ __launch_bounds__(256) void cnf_fwd_mfma(
    const float* __restrict__ x0, const float* __restrict__ W1,
    const float* __restrict__ b1, const float* __restrict__ W2,
    const float* __restrict__ b2, const float* __restrict__ W3,
    const float* __restrict__ b3, const int* __restrict__ nsp,
    float* __restrict__ xstate, float* __restrict__ traj,
    float* __restrict__ out, int rows, int i0, int S, int last) {
    __shared__ short hbuf[4][16 * 72]; // stride 72 shorts -> 2-way banks only
    __shared__ short xbuf[4][16 * 8];
    const int tid = threadIdx.x;
    const int w = tid >> 6;
    const int lane = tid & 63;
    const int c = lane & 15;
    const int q = lane >> 4;
    const int row0 = blockIdx.x * 64 + w * 16;
    short* hb = hbuf[w];
    short* xb = xbuf[w];

    const int n = *nsp;
    const float dt = 1.0f / (float)n;

    FragU a1[4], a2[4][2], a3[2];
    load_a1(a1, W1, b1, c, q);
    load_a2(a2, W2, c, q);
#pragma unroll
    for (int ks = 0; ks < 2; ++ks) { // W3 [8x64], rows 8..15 zero
        float f[8];
#pragma unroll
        for (int jj = 0; jj < 8; ++jj)
            f[jj] = (c < 8) ? W3[c * 64 + 32 * ks + 8 * q + jj] : 0.f;
#pragma unroll
        for (int p = 0; p < 4; ++p) a3[ks].u[p] = pkbf(f[2 * p], f[2 * p + 1]);
    }
    float b2v[4][4];
#pragma unroll
    for (int mt = 0; mt < 4; ++mt)
#pragma unroll
        for (int r = 0; r < 4; ++r) b2v[mt][r] = b2[16 * mt + 4 * q + r];
    float b3v[4];
#pragma unroll
    for (int r = 0; r < 4; ++r) b3v[r] = (q < 2) ? b3[4 * q + r] : 0.f;

    float xr[4] = {0.f, 0.f, 0.f, 0.f}; // fp32 master state, lanes q<2
    {
        const float* src = (i0 == 0) ? x0 : xstate;
        if (q < 2) {
            float4 v = *(const float4*)(src + (size_t)(row0 + c) * 8 + 4 * q);
            xr[0] = v.x; xr[1] = v.y; xr[2] = v.z; xr[3] = v.w;
        }
    }
    const v4f vzero = {0.f, 0.f, 0.f, 0.f};

    for (int s = 0; s < S; ++s) {
        const int i = i0 + s;
        if (i >= n) break;
        const float t = (float)i * dt;

        if (q < 2) {
            uint2 pw;
            pw.x = pkbf(xr[0], xr[1]);
            pw.y = pkbf(xr[2], xr[3]);
            *(uint2*)&xb[c * 8 + 4 * q] = pw;
        }
        FragU bf1;
        bf1.u[0] = bf1.u[1] = bf1.u[2] = bf1.u[3] = 0u;
        if (q == 0) {
            bf1.s = *(const v8s*)&xb[c * 8];
        } else if (q == 1) {
            bf1.u[0] = pkbf(t, 1.0f); // k=8: t, k=9: 1 (bias row)
        }

        v4f d1[4];
#pragma unroll
        for (int mt = 0; mt < 4; ++mt)
            d1[mt] = __builtin_amdgcn_mfma_f32_16x16x32_bf16(a1[mt].s, bf1.s, vzero, 0, 0, 0);

#pragma unroll
        for (int mt = 0; mt < 4; ++mt) {
            float t0 = ftanh(d1[mt][0]), t1 = ftanh(d1[mt][1]);
            float t2 = ftanh(d1[mt][2]), t3 = ftanh(d1[mt][3]);
            uint2 pw;
            pw.x = pkbf(t0, t1);
            pw.y = pkbf(t2, t3);
            *(uint2*)&hb[c * 72 + 16 * mt + 4 * q] = pw;
        }
        FragU bf2[2];
#pragma unroll
        for (int ks = 0; ks < 2; ++ks) bf2[ks].s = *(const v8s*)&hb[c * 72 + 32 * ks + 8 * q];

        v4f d2[4];
#pragma unroll
        for (int mt = 0; mt < 4; ++mt) {
            d2[mt] = __builtin_amdgcn_mfma_f32_16x16x32_bf16(a2[mt][0].s, bf2[0].s, vzero, 0, 0, 0);
            d2[mt] = __builtin_amdgcn_mfma_f32_16x16x32_bf16(a2[mt][1].s, bf2[1].s, d2[mt], 0, 0, 0);
        }
#pragma unroll
        for (int mt = 0; mt < 4; ++mt) {
            float t0 = ftanh(d2[mt][0] + b2v[mt][0]), t1 = ftanh(d2[mt][1] + b2v[mt][1]);
            float t2 = ftanh(d2[mt][2] + b2v[mt][2]), t3 = ftanh(d2[mt][3] + b2v[mt][3]);
            uint2 pw;
            pw.x = pkbf(t0, t1);
            pw.y = pkbf(t2, t3);
            *(uint2*)&hb[c * 72 + 16 * mt + 4 * q] = pw;
        }
        FragU bf3[2];
#pragma unroll
        for (int ks = 0; ks < 2; ++ks) bf3[ks].s = *(const v8s*)&hb[c * 72 + 32 * ks + 8 * q];

        v4f d3;
        d3 = __builtin_amdgcn_mfma_f32_16x16x32_bf16(a3[0].s, bf3[0].s, vzero, 0, 0, 0);
        d3 = __builtin_amdgcn_mfma_f32_16x16x32_bf16(a3[1].s, bf3[1].s, d3, 0, 0, 0);

        if (q < 2) {
#pragma unroll
            for (int r = 0; r < 4; ++r) xr[r] = fmaf(dt, d3[r] + b3v[r], xr[r]);
            float4 st = {xr[0], xr[1], xr[2], xr[3]};
            *(float4*)(traj + ((size_t)s * rows + row0 + c) * 8 + 4 * q) = st;
        }
    }

    if (q < 2) {
        float4 st = {xr[0], xr[1], xr[2], xr[3]};
        *(float4*)(xstate + (size_t)(row0 + c) * 8 + 4 * q) = st;
        if (last) *(float4*)(out + (size_t)(row0 + c) * 8 + 4 * q) = st;
    }
}

// ------------- Kernel B: MFMA log-det, parallel over (tile, step-group) ------
// gsum = sum_j w3c[j](1-tanh^2(z2_j+b2_j)) * s_j,  z2 = W2@h1', s = W2@u,
// u = (1-h1'^2)*w1r, h1' = tanh(W1@[x_new;t;1]).
__global__ __launch_bounds__(256) void cnf_bwd_mfma(
    const float* __restrict__ W1, const float* __restrict__ b1,
    const float* __restrict__ W2, const float* __restrict__ b2,
    const int* __restrict__ nsp, const float* __restrict__ traj,
    float* __restrict__ ld, int rows, int i0, int S) {
    __shared__ short hbuf[4][16 * 72];
    __shared__ short ubuf[4][16 * 72];
    __shared__ short xbuf[4][16 * 8];
    const int tid = threadIdx.x;
    const int w = tid >> 6;
    const int lane = tid & 63;
    const int c = lane & 15;
    const int q = lane >> 4;
    const int ntile = rows / 16; // 2048
    const int task = blockIdx.x * 4 + w;
    const int tile = task % ntile;
    const int s0 = (task / ntile) * KSTEP;
    if (s0 >= S) return;
    const int row0 = tile * 16;
    short* hb = hbuf[w];
    short* ub = ubuf[w];
    short* xb = xbuf[w];

    const int n = *nsp;
    const float dt = 1.0f / (float)n;

    FragU a1[4], a2[4][2];
    load_a1(a1, W1, b1, c, q);
    load_a2(a2, W2, c, q);
    float b2v[4][4], w3cv[4][4], w1rv[4][4];
#pragma unroll
    for (int mt = 0; mt < 4; ++mt)
#pragma unroll
        for (int r = 0; r < 4; ++r) {
            const int j = 16 * mt + 4 * q + r;
            b2v[mt][r] = b2[j];
            w3cv[mt][r] = g_w3c[j];
            w1rv[mt][r] = g_w1r[j];
        }

    const v4f vzero = {0.f, 0.f, 0.f, 0.f};
    float g = 0.f;

    for (int k = 0; k < KSTEP; ++k) {
        const int s = s0 + k;
        if (s >= S || i0 + s >= n) break;
        const float t = (float)(i0 + s) * dt;

        if (q < 2) {
            float4 v = *(const float4*)(traj + ((size_t)s * rows + row0 + c) * 8 + 4 * q);
            uint2 pw;
            pw.x = pkbf(v.x, v.y);
            pw.y = pkbf(v.z, v.w);
            *(uint2*)&xb[c * 8 + 4 * q] = pw;
        }
        FragU bf1;
        bf1.u[0] = bf1.u[1] = bf1.u[2] = bf1.u[3] = 0u;
        if (q == 0) {
            bf1.s = *(const v8s*)&xb[c * 8];
        } else if (q == 1) {
            bf1.u[0] = pkbf(t, 1.0f);
        }

        v4f d1[4];
#pragma unroll
        for (int mt = 0; mt < 4; ++mt)
            d1[mt] = __builtin_amdgcn_mfma_f32_16x16x32_bf16(a1[mt].s, bf1.s, vzero, 0, 0, 0);

        // h1' -> hb (bf16), u = (1-h1'^2)*w1r -> ub (bf16)
#pragma unroll
        for (int mt = 0; mt < 4; ++mt) {
            float t0 = ftanh(d1[mt][0]), t1 = ftanh(d1[mt][1]);
            float t2 = ftanh(d1[mt][2]), t3 = ftanh(d1[mt][3]);
            uint2 ph;
            ph.x = pkbf(t0, t1);
            ph.y = pkbf(t2, t3);
            *(uint2*)&hb[c * 72 + 16 * mt + 4 * q] = ph;
            float u0 = fmaf(-t0, t0, 1.0f) * w1rv[mt][0];
            float u1 = fmaf(-t1, t1, 1.0f) * w1rv[mt][1];
            float u2 = fmaf(-t2, t2, 1.0f) * w1rv[mt][2];
            float u3 = fmaf(-t3, t3, 1.0f) * w1rv[mt][3];
            uint2 pu;
            pu.x = pkbf(u0, u1);
            pu.y = pkbf(u2, u3);
            *(uint2*)&ub[c * 72 + 16 * mt + 4 * q] = pu;
        }
        FragU bh[2], bu[2];
#pragma unroll
        for (int ks = 0; ks < 2; ++ks) {
            bh[ks].s = *(const v8s*)&hb[c * 72 + 32 * ks + 8 * q];
            bu[ks].s = *(const v8s*)&ub[c * 72 + 32 * ks + 8 * q];
        }

        v4f d2[4], ds[4];
#pragma unroll
        for (int mt = 0; mt < 4; ++mt) {
            d2[mt] = __builtin_amdgcn_mfma_f32_16x16x32_bf16(a2[mt][0].s, bh[0].s, vzero, 0, 0, 0);
            d2[mt] = __builtin_amdgcn_mfma_f32_16x16x32_bf16(a2[mt][1].s, bh[1].s, d2[mt], 0, 0, 0);
            ds[mt] = __builtin_amdgcn_mfma_f32_16x16x32_bf16(a2[mt][0].s, bu[0].s, vzero, 0, 0, 0);
            ds[mt] = __builtin_amdgcn_mfma_f32_16x16x32_bf16(a2[mt][1].s, bu[1].s, ds[mt], 0, 0, 0);
        }

#pragma unroll
        for (int mt = 0; mt < 4; ++mt)
#pragma unroll
            for (int r = 0; r < 4; ++r) {
                float th2 = ftanh(d2[mt][r] + b2v[mt][r]);
                g = fmaf(w3cv[mt][r] * fmaf(-th2, th2, 1.0f), ds[mt][r], g);
            }
    }

    // reduce over the 4 q-lanes holding the same batch row c
    g += __shfl_xor(g, 16);
    g += __shfl_xor(g, 32);
    if (q == 0) atomicAdd(&ld[row0 + c], dt * g);
}

// ------------- Fallback: fp32 monolith (used only if ws too small) -----------
__global__ __launch_bounds__(64) void cnf_mono(
    const float* __restrict__ x0, const float* __restrict__ W1,
    const float* __restrict__ b1, const float* __restrict__ W2,
    const float* __restrict__ b2, const float* __restrict__ b3,
    const int* __restrict__ nsp, float* __restrict__ out, int rows) {
    const int lane = threadIdx.x;
    const int row = blockIdx.x * 64 + lane;
    const int n = *nsp;
    const float dt = 1.0f / (float)n;
    float x[8];
    {
        const float4* p = (const float4*)(x0 + (size_t)row * 8);
        float4 a = p[0], b = p[1];
        x[0] = a.x; x[1] = a.y; x[2] = a.z; x[3] = a.w;
        x[4] = b.x; x[5] = b.y; x[6] = b.z; x[7] = b.w;
    }
    float ld = 0.f;
    for (int i = 0; i < n; ++i) {
        const float t = (float)i * dt;
        float h1[64];
#pragma unroll
        for (int j = 0; j < 64; ++j) {
            const float* w = W1 + j * 9;
            float a = fmaf(w[8], t, b1[j]);
#pragma unroll
            for (int k = 0; k < 8; ++k) a = fmaf(w[k], x[k], a);
            h1[j] = ftanh(a);
        }
        float dx[8];
#pragma unroll
        for (int d = 0; d < 8; ++d) dx[d] = b3[d];
#pragma unroll 4
        for (int j = 0; j < 64; ++j) {
            const float* w = W2 + j * 64;
            float a0 = 0.f, a1 = 0.f, a2 = 0.f, a3 = 0.f;
#pragma unroll
            for (int h = 0; h < 64; h += 4) {
                a0 = fmaf(w[h], h1[h], a0);
                a1 = fmaf(w[h + 1], h1[h + 1], a1);
                a2 = fmaf(w[h + 2], h1[h + 2], a2);
                a3 = fmaf(w[h + 3], h1[h + 3], a3);
            }
            float h2 = ftanh(((a0 + a1) + (a2 + a3)) + b2[j]);
            const float* w3t = g_w3t + j * 8;
#pragma unroll
            for (int d = 0; d < 8; ++d) dx[d] = fmaf(w3t[d], h2, dx[d]);
        }
#pragma unroll
        for (int d = 0; d < 8; ++d) x[d] = fmaf(dt, dx[d], x[d]);
        float h1p[64], uu[64];
#pragma unroll
        for (int j = 0; j < 64; ++j) {
            const float* w = W1 + j * 9;
            float a = fmaf(w[8], t, b1[j]);
#pragma unroll
            for (int k = 0; k < 8; ++k) a = fmaf(w[k], x[k], a);
            float th = ftanh(a);
            h1p[j] = th;
            uu[j] = fmaf(-th, th, 1.0f) * g_w1r[j];
        }
        float gs = 0.f;
#pragma unroll 2
        for (int j = 0; j < 64; ++j) {
            const float* w = W2 + j * 64;
            float a0 = 0.f, a1 = 0.f, s0 = 0.f, s1 = 0.f;
#pragma unroll
            for (int h = 0; h < 64; h += 2) {
                float w0 = w[h], w1 = w[h + 1];
                a0 = fmaf(w0, h1p[h], a0);
                a1 = fmaf(w1, h1p[h + 1], a1);
                s0 = fmaf(w0, uu[h], s0);
                s1 = fmaf(w1, uu[h + 1], s1);
            }
            float th2 = ftanh((a0 + a1) + b2[j]);
            float dz2 = g_w3c[j] * fmaf(-th2, th2, 1.0f);
            gs = fmaf(dz2, s0 + s1, gs);
        }
        ld = fmaf(dt, gs, ld);
    }
    float4* po = (float4*)(out + (size_t)row * 8);
    float4 o0, o1;
    o0.x = x[0]; o0.y = x[1]; o0.z = x[2]; o0.w = x[3];
    o1.x = x[4]; o1.y = x[5]; o1.z = x[6]; o1.w = x[7];
    po[0] = o0; po[1] = o1;
    out[(size_t)rows * 8 + row] = ld;
}

extern "C" void kernel_launch(void* const* d_in, const int* in_sizes, int n_in,
                              void* d_out, int out_size, void* d_ws, size_t ws_size,
                              hipStream_t stream) {
    const float* x0 = (const float*)d_in[0];
    const float* W1 = (const float*)d_in[1];
    const float* b1 = (const float*)d_in[2];
    const float* W2 = (const float*)d_in[3];
    const float* b2 = (const float*)d_in[4];
    const float* W3 = (const float*)d_in[5];
    const float* b3 = (const float*)d_in[6];
    const int* ns = (const int*)d_in[7];
    float* out = (float*)d_out;
    const int rows = in_sizes[0] / 8; // 32768
    const int TOT = 100;              // reference STEPS (device n also guards)

    hipLaunchKernelGGL(cnf_prep, dim3(1), dim3(64), 0, stream, W1, W3);

    const size_t xs_bytes = (size_t)rows * 8 * 4;
    const size_t step_bytes = (size_t)rows * 8 * 4;
    int S = TOT;
    while (S > 1 && xs_bytes + (size_t)S * step_bytes > ws_size) --S;

    if (xs_bytes + (size_t)S * step_bytes > ws_size) {
        hipLaunchKernelGGL(cnf_mono, dim3(rows / 64), dim3(64), 0, stream,
                           x0, W1, b1, W2, b2, b3, ns, out, rows);
        return;
    }

    float* xstate = (float*)d_ws;
    float* traj = (float*)((char*)d_ws + xs_bytes);
    float* ldp = out + (size_t)rows * 8;

    (void)hipMemsetAsync(ldp, 0, (size_t)rows * 4, stream);

    const int ntile = rows / 16; // 2048
    const int nch = (TOT + S - 1) / S;
    for (int c = 0; c < nch; ++c) {
        const int i0 = c * S;
        const int Seff = (TOT - i0 < S) ? (TOT - i0) : S;
        const int last = (c == nch - 1) ? 1 : 0;
        hipLaunchKernelGGL(cnf_fwd_mfma, dim3(rows / 64), dim3(256), 0, stream,
                           x0, W1, b1, W2, b2, W3, b3, ns, xstate, traj, out,
                           rows, i0, Seff, last);
        const int sgroups = (Seff + KSTEP - 1) / KSTEP;
        const int tasks = ntile * sgroups;
        hipLaunchKernelGGL(cnf_bwd_mfma, dim3((tasks + 3) / 4), dim3(256), 0, stream,
                           W1, b1, W2, b2, ns, traj, ldp, rows, i0, Seff);
    }
}

// Round 8
// 410.653 us; speedup vs baseline: 24.6043x; 1.2831x over previous
//
#include <hip/hip_runtime.h>
#include <hip/hip_bf16.h>

// ContinuousNormalizingFlow: B=32768 rows, D=8, H=64, 100 Euler steps.
// R8: single fused MFMA kernel. 16 rows/wave, weights persistent in VGPR
// A-frags, C->B layout transforms via ds_bpermute (__shfl) — no LDS, no
// trajectory workspace, no atomics. fwd(i) then bwd(i) at in-register x_new.

__device__ float g_w1r[64]; // sum_{k<8} W1[j][k]
__device__ float g_w3c[64]; // sum_d W3[d][j]

__global__ void cnf_prep(const float* __restrict__ W1, const float* __restrict__ W3) {
    int h = threadIdx.x; // 64 threads
    float s = 0.f;
#pragma unroll
    for (int k = 0; k < 8; ++k) s += W1[h * 9 + k];
    g_w1r[h] = s;
    float c = 0.f;
#pragma unroll
    for (int d = 0; d < 8; ++d) c += W3[d * 64 + h];
    g_w3c[h] = c;
}

__device__ __forceinline__ float ftanh(float x) {
    // tanh(x) = 1 - 2/(exp(2x)+1); v_exp_f32 computes 2^x, inf-safe both ends.
    float e = __builtin_amdgcn_exp2f(x * 2.885390081777926815f); // 2*log2(e)
    float r = __builtin_amdgcn_rcpf(e + 1.0f);
    return fmaf(-2.0f, r, 1.0f);
}

typedef __attribute__((ext_vector_type(8))) short v8s; // 8 bf16 (4 VGPRs)
typedef __attribute__((ext_vector_type(4))) float v4f; // MFMA C/D

union FragU {
    v8s s;
    unsigned u[4];
};

__device__ __forceinline__ unsigned pkbf(float a, float b) {
    // packed bf16 cvt (v_cvt_pk_bf16_f32 on gfx950); a -> low half
    __hip_bfloat162 h = __float22bfloat162_rn(float2{a, b});
    unsigned r;
    __builtin_memcpy(&r, &h, sizeof(r));
    return r;
}

// mfma_f32_16x16x32_bf16 layouts:
//   A[m=lane&15][k=(lane>>4)*8+j], B[k=(lane>>4)*8+j][n=lane&15],
//   C/D[row=(lane>>4)*4+reg][col=lane&15].
__device__ __forceinline__ void load_a1(FragU a1[4], const float* W1,
                                        const float* b1, int c, int q) {
#pragma unroll
    for (int mt = 0; mt < 4; ++mt) {
        const int m = 16 * mt + c;
        float f[8];
#pragma unroll
        for (int jj = 0; jj < 8; ++jj) {
            const int k = 8 * q + jj;
            f[jj] = (k < 9) ? W1[m * 9 + k] : ((k == 9) ? b1[m] : 0.f);
        }
#pragma unroll
        for (int p = 0; p < 4; ++p) a1[mt].u[p] = pkbf(f[2 * p], f[2 * p + 1]);
    }
}
__device__ __forceinline__ void load_a2(FragU a2[4][2], const float* W2,
                                        int c, int q) {
#pragma unroll
    for (int mt = 0; mt < 4; ++mt)
#pragma unroll
        for (int ks = 0; ks < 2; ++ks) {
            const int m = 16 * mt + c;
            float f[8];
#pragma unroll
            for (int jj = 0; jj < 8; ++jj) f[jj] = W2[m * 64 + 32 * ks + 8 * q + jj];
#pragma unroll
            for (int p = 0; p < 4; ++p) a2[mt][ks].u[p] = pkbf(f[2 * p], f[2 * p + 1]);
        }
}

// C-layout (per-mt packed uint2: .x = regs 0,1; .y = regs 2,3) -> B-layout.
// Target (c,q,ks,p): k = 32ks+8q+2p, src lane = c+16*((2q+(p>>1))&3),
// src mt = 2ks + (q>=2), src half = p&1. One shfl pair + select per dword.
__device__ __forceinline__ void xform(const uint2 ph[4], int lA, int lB,
                                      bool qlo, FragU bh[2]) {
#pragma unroll
    for (int ks = 0; ks < 2; ++ks) {
        unsigned lo, hi;
        lo = __shfl(ph[2 * ks].x, lA); hi = __shfl(ph[2 * ks + 1].x, lA);
        bh[ks].u[0] = qlo ? lo : hi;
        lo = __shfl(ph[2 * ks].y, lA); hi = __shfl(ph[2 * ks + 1].y, lA);
        bh[ks].u[1] = qlo ? lo : hi;
        lo = __shfl(ph[2 * ks].x, lB); hi = __shfl(ph[2 * ks + 1].x, lB);
        bh[ks].u[2] = qlo ? lo : hi;
        lo = __shfl(ph[2 * ks].y, lB); hi = __shfl(ph[2 * ks + 1].y, lB);
        bh[ks].u[3] = qlo ? lo : hi;
    }
}

// B-frag for xt = [x; t; 1]: q=0 holds x[0..7], q=1 holds {t,1,0...}, else 0.
__device__ __forceinline__ FragU make_bx(const float xr[4], float t, int c, int q) {
    unsigned px = pkbf(xr[0], xr[1]);
    unsigned py = pkbf(xr[2], xr[3]);
    unsigned u0 = __shfl(px, c), u1 = __shfl(py, c);
    unsigned u2 = __shfl(px, c + 16), u3 = __shfl(py, c + 16);
    FragU b;
    if (q == 0) {
        b.u[0] = u0; b.u[1] = u1; b.u[2] = u2; b.u[3] = u3;
    } else if (q == 1) {
        b.u[0] = pkbf(t, 1.0f); b.u[1] = 0u; b.u[2] = 0u; b.u[3] = 0u;
    } else {
        b.u[0] = 0u; b.u[1] = 0u; b.u[2] = 0u; b.u[3] = 0u;
    }
    return b;
}

__global__ __launch_bounds__(256, 2) void cnf_fused(
    const float* __restrict__ x0, const float* __restrict__ W1,
    const float* __restrict__ b1, const float* __restrict__ W2,
    const float* __restrict__ b2, const float* __restrict__ W3,
    const float* __restrict__ b3, const int* __restrict__ nsp,
    float* __restrict__ out, int rows) {
    const int tid = threadIdx.x;
    const int w = tid >> 6;
    const int lane = tid & 63;
    const int c = lane & 15;
    const int q = lane >> 4;
    const int row0 = blockIdx.x * 64 + w * 16;

    const int n = *nsp;
    const float dt = 1.0f / (float)n;

    // ---- persistent weight frags ----
    FragU a1[4], a2[4][2], a3[2];
    load_a1(a1, W1, b1, c, q);
    load_a2(a2, W2, c, q);
#pragma unroll
    for (int ks = 0; ks < 2; ++ks) { // W3 [8x64], rows 8..15 zero
        float f[8];
#pragma unroll
        for (int jj = 0; jj < 8; ++jj)
            f[jj] = (c < 8) ? W3[c * 64 + 32 * ks + 8 * q + jj] : 0.f;
#pragma unroll
        for (int p = 0; p < 4; ++p) a3[ks].u[p] = pkbf(f[2 * p], f[2 * p + 1]);
    }
    float b2v[4][4], w3cv[4][4], w1rv[4][4];
#pragma unroll
    for (int mt = 0; mt < 4; ++mt)
#pragma unroll
        for (int r = 0; r < 4; ++r) {
            const int j = 16 * mt + 4 * q + r;
            b2v[mt][r] = b2[j];
            w3cv[mt][r] = g_w3c[j];
            w1rv[mt][r] = g_w1r[j];
        }
    float b3v[4];
#pragma unroll
    for (int r = 0; r < 4; ++r) b3v[r] = (q < 2) ? b3[4 * q + r] : 0.f;

    const int lA = c + 16 * ((2 * q) & 3);     // xform src lanes (fixed)
    const int lB = c + 16 * ((2 * q + 1) & 3);
    const bool qlo = (q < 2);

    float xr[4] = {0.f, 0.f, 0.f, 0.f}; // fp32 master state, lanes q<2
    if (q < 2) {
        float4 v = *(const float4*)(x0 + (size_t)(row0 + c) * 8 + 4 * q);
        xr[0] = v.x; xr[1] = v.y; xr[2] = v.z; xr[3] = v.w;
    }
    const v4f vzero = {0.f, 0.f, 0.f, 0.f};
    float g = 0.f;

    for (int i = 0; i < n; ++i) {
        const float t = (float)i * dt;

        // ================= forward: x -> x_new =================
        FragU bx = make_bx(xr, t, c, q);
        v4f d1[4];
#pragma unroll
        for (int mt = 0; mt < 4; ++mt)
            d1[mt] = __builtin_amdgcn_mfma_f32_16x16x32_bf16(a1[mt].s, bx.s, vzero, 0, 0, 0);

        uint2 ph[4];
#pragma unroll
        for (int mt = 0; mt < 4; ++mt) {
            float t0 = ftanh(d1[mt][0]), t1 = ftanh(d1[mt][1]);
            float t2 = ftanh(d1[mt][2]), t3 = ftanh(d1[mt][3]);
            ph[mt].x = pkbf(t0, t1);
            ph[mt].y = pkbf(t2, t3);
        }
        FragU bh[2];
        xform(ph, lA, lB, qlo, bh);

        v4f d2[4];
#pragma unroll
        for (int mt = 0; mt < 4; ++mt) {
            d2[mt] = __builtin_amdgcn_mfma_f32_16x16x32_bf16(a2[mt][0].s, bh[0].s, vzero, 0, 0, 0);
            d2[mt] = __builtin_amdgcn_mfma_f32_16x16x32_bf16(a2[mt][1].s, bh[1].s, d2[mt], 0, 0, 0);
        }
#pragma unroll
        for (int mt = 0; mt < 4; ++mt) {
            float t0 = ftanh(d2[mt][0] + b2v[mt][0]), t1 = ftanh(d2[mt][1] + b2v[mt][1]);
            float t2 = ftanh(d2[mt][2] + b2v[mt][2]), t3 = ftanh(d2[mt][3] + b2v[mt][3]);
            ph[mt].x = pkbf(t0, t1);
            ph[mt].y = pkbf(t2, t3);
        }
        FragU bh2[2];
        xform(ph, lA, lB, qlo, bh2);

        v4f d3;
        d3 = __builtin_amdgcn_mfma_f32_16x16x32_bf16(a3[0].s, bh2[0].s, vzero, 0, 0, 0);
        d3 = __builtin_amdgcn_mfma_f32_16x16x32_bf16(a3[1].s, bh2[1].s, d3, 0, 0, 0);

        if (q < 2) {
#pragma unroll
            for (int r = 0; r < 4; ++r) xr[r] = fmaf(dt, d3[r] + b3v[r], xr[r]);
        }

        // ================= backward at x_new (same t) =================
        FragU bxp = make_bx(xr, t, c, q);
        v4f d1p[4];
#pragma unroll
        for (int mt = 0; mt < 4; ++mt)
            d1p[mt] = __builtin_amdgcn_mfma_f32_16x16x32_bf16(a1[mt].s, bxp.s, vzero, 0, 0, 0);

        uint2 phh[4], phu[4];
#pragma unroll
        for (int mt = 0; mt < 4; ++mt) {
            float t0 = ftanh(d1p[mt][0]), t1 = ftanh(d1p[mt][1]);
            float t2 = ftanh(d1p[mt][2]), t3 = ftanh(d1p[mt][3]);
            phh[mt].x = pkbf(t0, t1);
            phh[mt].y = pkbf(t2, t3);
            float u0 = fmaf(-t0, t0, 1.0f) * w1rv[mt][0];
            float u1 = fmaf(-t1, t1, 1.0f) * w1rv[mt][1];
            float u2 = fmaf(-t2, t2, 1.0f) * w1rv[mt][2];
            float u3 = fmaf(-t3, t3, 1.0f) * w1rv[mt][3];
            phu[mt].x = pkbf(u0, u1);
            phu[mt].y = pkbf(u2, u3);
        }
        FragU bhp[2], bup[2];
        xform(phh, lA, lB, qlo, bhp);
        xform(phu, lA, lB, qlo, bup);

        v4f d2p[4], dsp[4];
#pragma unroll
        for (int mt = 0; mt < 4; ++mt) {
            d2p[mt] = __builtin_amdgcn_mfma_f32_16x16x32_bf16(a2[mt][0].s, bhp[0].s, vzero, 0, 0, 0);
            d2p[mt] = __builtin_amdgcn_mfma_f32_16x16x32_bf16(a2[mt][1].s, bhp[1].s, d2p[mt], 0, 0, 0);
            dsp[mt] = __builtin_amdgcn_mfma_f32_16x16x32_bf16(a2[mt][0].s, bup[0].s, vzero, 0, 0, 0);
            dsp[mt] = __builtin_amdgcn_mfma_f32_16x16x32_bf16(a2[mt][1].s, bup[1].s, dsp[mt], 0, 0, 0);
        }
#pragma unroll
        for (int mt = 0; mt < 4; ++mt)
#pragma unroll
            for (int r = 0; r < 4; ++r) {
                float th2 = ftanh(d2p[mt][r] + b2v[mt][r]);
                g = fmaf(w3cv[mt][r] * fmaf(-th2, th2, 1.0f), dsp[mt][r], g);
            }
    }

    // ---- epilogue ----
    g += __shfl_xor(g, 16);
    g += __shfl_xor(g, 32);
    if (q < 2) {
        float4 st = {xr[0], xr[1], xr[2], xr[3]};
        *(float4*)(out + (size_t)(row0 + c) * 8 + 4 * q) = st;
    }
    if (q == 0) out[(size_t)rows * 8 + row0 + c] = dt * g;
}

extern "C" void kernel_launch(void* const* d_in, const int* in_sizes, int n_in,
                              void* d_out, int out_size, void* d_ws, size_t ws_size,
                              hipStream_t stream) {
    const float* x0 = (const float*)d_in[0];
    const float* W1 = (const float*)d_in[1];
    const float* b1 = (const float*)d_in[2];
    const float* W2 = (const float*)d_in[3];
    const float* b2 = (const float*)d_in[4];
    const float* W3 = (const float*)d_in[5];
    const float* b3 = (const float*)d_in[6];
    const int* ns = (const int*)d_in[7];
    float* out = (float*)d_out;
    const int rows = in_sizes[0] / 8; // 32768

    hipLaunchKernelGGL(cnf_prep, dim3(1), dim3(64), 0, stream, W1, W3);
    hipLaunchKernelGGL(cnf_fused, dim3(rows / 64), dim3(256), 0, stream,
                       x0, W1, b1, W2, b2, W3, b3, ns, out, rows);
}

// Round 9
// 332.387 us; speedup vs baseline: 30.3978x; 1.2355x over previous
//
#include <hip/hip_runtime.h>
#include <hip/hip_bf16.h>

// ContinuousNormalizingFlow: B=32768 rows, D=8, H=64, 100 Euler steps.
// R9: fused MFMA kernel, restructured so iteration i computes bwd(i-1) and
// fwd(i) from ONE shared L1 evaluation at (x_i, t_{i-1}):
//   z1_fwd = z1_bwd + dt*W1[:,8]   (exact)
//   dh1 = (1-th1b^2)*dt*w1t        (Taylor, err ~4e-6 << bf16 noise)
//   dz2 = W2@dh1; th2_fwd = th2b + (1-th2b^2)*dz2  (err ~3e-7)
// Halves tanh count (64 -> 32 per wave-step), which dominated R8's VALU issue.

__device__ float g_w1r[64]; // sum_{k<8} W1[j][k]
__device__ float g_w3c[64]; // sum_d W3[d][j]

__global__ void cnf_prep(const float* __restrict__ W1, const float* __restrict__ W3) {
    int h = threadIdx.x; // 64 threads
    float s = 0.f;
#pragma unroll
    for (int k = 0; k < 8; ++k) s += W1[h * 9 + k];
    g_w1r[h] = s;
    float c = 0.f;
#pragma unroll
    for (int d = 0; d < 8; ++d) c += W3[d * 64 + h];
    g_w3c[h] = c;
}

__device__ __forceinline__ float ftanh(float x) {
    // tanh(x) = 1 - 2/(exp(2x)+1); v_exp_f32 computes 2^x, inf-safe both ends.
    float e = __builtin_amdgcn_exp2f(x * 2.885390081777926815f); // 2*log2(e)
    float r = __builtin_amdgcn_rcpf(e + 1.0f);
    return fmaf(-2.0f, r, 1.0f);
}

typedef __attribute__((ext_vector_type(8))) short v8s; // 8 bf16 (4 VGPRs)
typedef __attribute__((ext_vector_type(4))) float v4f; // MFMA C/D

union FragU {
    v8s s;
    unsigned u[4];
};

__device__ __forceinline__ unsigned pkbf(float a, float b) {
    // packed bf16 cvt (v_cvt_pk_bf16_f32 on gfx950); a -> low half
    __hip_bfloat162 h = __float22bfloat162_rn(float2{a, b});
    unsigned r;
    __builtin_memcpy(&r, &h, sizeof(r));
    return r;
}

// mfma_f32_16x16x32_bf16 layouts:
//   A[m=lane&15][k=(lane>>4)*8+j], B[k=(lane>>4)*8+j][n=lane&15],
//   C/D[row=(lane>>4)*4+reg][col=lane&15].
__device__ __forceinline__ void load_a1(FragU a1[4], const float* W1,
                                        const float* b1, int c, int q) {
#pragma unroll
    for (int mt = 0; mt < 4; ++mt) {
        const int m = 16 * mt + c;
        float f[8];
#pragma unroll
        for (int jj = 0; jj < 8; ++jj) {
            const int k = 8 * q + jj;
            f[jj] = (k < 9) ? W1[m * 9 + k] : ((k == 9) ? b1[m] : 0.f);
        }
#pragma unroll
        for (int p = 0; p < 4; ++p) a1[mt].u[p] = pkbf(f[2 * p], f[2 * p + 1]);
    }
}
__device__ __forceinline__ void load_a2(FragU a2[4][2], const float* W2,
                                        int c, int q) {
#pragma unroll
    for (int mt = 0; mt < 4; ++mt)
#pragma unroll
        for (int ks = 0; ks < 2; ++ks) {
            const int m = 16 * mt + c;
            float f[8];
#pragma unroll
            for (int jj = 0; jj < 8; ++jj) f[jj] = W2[m * 64 + 32 * ks + 8 * q + jj];
#pragma unroll
            for (int p = 0; p < 4; ++p) a2[mt][ks].u[p] = pkbf(f[2 * p], f[2 * p + 1]);
        }
}

// C-layout (per-mt packed uint2: .x = regs 0,1; .y = regs 2,3) -> B-layout.
__device__ __forceinline__ void xform(const uint2 ph[4], int lA, int lB,
                                      bool qlo, FragU bh[2]) {
#pragma unroll
    for (int ks = 0; ks < 2; ++ks) {
        unsigned lo, hi;
        lo = __shfl(ph[2 * ks].x, lA); hi = __shfl(ph[2 * ks + 1].x, lA);
        bh[ks].u[0] = qlo ? lo : hi;
        lo = __shfl(ph[2 * ks].y, lA); hi = __shfl(ph[2 * ks + 1].y, lA);
        bh[ks].u[1] = qlo ? lo : hi;
        lo = __shfl(ph[2 * ks].x, lB); hi = __shfl(ph[2 * ks + 1].x, lB);
        bh[ks].u[2] = qlo ? lo : hi;
        lo = __shfl(ph[2 * ks].y, lB); hi = __shfl(ph[2 * ks + 1].y, lB);
        bh[ks].u[3] = qlo ? lo : hi;
    }
}

// B-frag for xt = [x; t; 1]: q=0 holds x[0..7], q=1 holds {t,1,0...}, else 0.
__device__ __forceinline__ FragU make_bx(const float xr[4], float t, int c, int q) {
    unsigned px = pkbf(xr[0], xr[1]);
    unsigned py = pkbf(xr[2], xr[3]);
    unsigned u0 = __shfl(px, c), u1 = __shfl(py, c);
    unsigned u2 = __shfl(px, c + 16), u3 = __shfl(py, c + 16);
    FragU b;
    if (q == 0) {
        b.u[0] = u0; b.u[1] = u1; b.u[2] = u2; b.u[3] = u3;
    } else if (q == 1) {
        b.u[0] = pkbf(t, 1.0f); b.u[1] = 0u; b.u[2] = 0u; b.u[3] = 0u;
    } else {
        b.u[0] = 0u; b.u[1] = 0u; b.u[2] = 0u; b.u[3] = 0u;
    }
    return b;
}

__global__ __launch_bounds__(256, 2) void cnf_fused(
    const float* __restrict__ x0, const float* __restrict__ W1,
    const float* __restrict__ b1, const float* __restrict__ W2,
    const float* __restrict__ b2, const float* __restrict__ W3,
    const float* __restrict__ b3, const int* __restrict__ nsp,
    float* __restrict__ out, int rows) {
    const int tid = threadIdx.x;
    const int w = tid >> 6;
    const int lane = tid & 63;
    const int c = lane & 15;
    const int q = lane >> 4;
    const int row0 = blockIdx.x * 64 + w * 16;

    const int n = *nsp;
    const float dt = 1.0f / (float)n;

    // ---- persistent weight frags + per-lane constants ----
    FragU a1[4], a2[4][2], a3[2];
    load_a1(a1, W1, b1, c, q);
    load_a2(a2, W2, c, q);
#pragma unroll
    for (int ks = 0; ks < 2; ++ks) { // W3 [8x64], rows 8..15 zero
        float f[8];
#pragma unroll
        for (int jj = 0; jj < 8; ++jj)
            f[jj] = (c < 8) ? W3[c * 64 + 32 * ks + 8 * q + jj] : 0.f;
#pragma unroll
        for (int p = 0; p < 4; ++p) a3[ks].u[p] = pkbf(f[2 * p], f[2 * p + 1]);
    }
    float b2v[4][4], w3cv[4][4], w1rv[4][4], dtw1t[4][4];
#pragma unroll
    for (int mt = 0; mt < 4; ++mt)
#pragma unroll
        for (int r = 0; r < 4; ++r) {
            const int j = 16 * mt + 4 * q + r;
            b2v[mt][r] = b2[j];
            w3cv[mt][r] = g_w3c[j];
            w1rv[mt][r] = g_w1r[j];
            dtw1t[mt][r] = dt * W1[j * 9 + 8];
        }
    float b3v[4];
#pragma unroll
    for (int r = 0; r < 4; ++r) b3v[r] = (q < 2) ? b3[4 * q + r] : 0.f;

    const int lA = c + 16 * ((2 * q) & 3);     // xform src lanes (fixed)
    const int lB = c + 16 * ((2 * q + 1) & 3);
    const bool qlo = (q < 2);

    float xr[4] = {0.f, 0.f, 0.f, 0.f}; // fp32 master state, lanes q<2
    if (q < 2) {
        float4 v = *(const float4*)(x0 + (size_t)(row0 + c) * 8 + 4 * q);
        xr[0] = v.x; xr[1] = v.y; xr[2] = v.z; xr[3] = v.w;
    }
    const v4f vzero = {0.f, 0.f, 0.f, 0.f};
    float g = 0.f;

    // ================= iteration 0: pure forward at (x0, t=0) =================
    {
        FragU bx = make_bx(xr, 0.0f, c, q);
        v4f d1[4];
#pragma unroll
        for (int mt = 0; mt < 4; ++mt)
            d1[mt] = __builtin_amdgcn_mfma_f32_16x16x32_bf16(a1[mt].s, bx.s, vzero, 0, 0, 0);
        uint2 ph[4];
#pragma unroll
        for (int mt = 0; mt < 4; ++mt) {
            float t0 = ftanh(d1[mt][0]), t1 = ftanh(d1[mt][1]);
            float t2 = ftanh(d1[mt][2]), t3 = ftanh(d1[mt][3]);
            ph[mt].x = pkbf(t0, t1);
            ph[mt].y = pkbf(t2, t3);
        }
        FragU bh[2];
        xform(ph, lA, lB, qlo, bh);
        v4f d2[4];
#pragma unroll
        for (int mt = 0; mt < 4; ++mt) {
            d2[mt] = __builtin_amdgcn_mfma_f32_16x16x32_bf16(a2[mt][0].s, bh[0].s, vzero, 0, 0, 0);
            d2[mt] = __builtin_amdgcn_mfma_f32_16x16x32_bf16(a2[mt][1].s, bh[1].s, d2[mt], 0, 0, 0);
        }
#pragma unroll
        for (int mt = 0; mt < 4; ++mt) {
            float t0 = ftanh(d2[mt][0] + b2v[mt][0]), t1 = ftanh(d2[mt][1] + b2v[mt][1]);
            float t2 = ftanh(d2[mt][2] + b2v[mt][2]), t3 = ftanh(d2[mt][3] + b2v[mt][3]);
            ph[mt].x = pkbf(t0, t1);
            ph[mt].y = pkbf(t2, t3);
        }
        FragU bh2[2];
        xform(ph, lA, lB, qlo, bh2);
        v4f d3;
        d3 = __builtin_amdgcn_mfma_f32_16x16x32_bf16(a3[0].s, bh2[0].s, vzero, 0, 0, 0);
        d3 = __builtin_amdgcn_mfma_f32_16x16x32_bf16(a3[1].s, bh2[1].s, d3, 0, 0, 0);
        if (q < 2) {
#pragma unroll
            for (int r = 0; r < 4; ++r) xr[r] = fmaf(dt, d3[r] + b3v[r], xr[r]);
        }
    }

    // ====== iterations i = 1..n-1: bwd(i-1) + fwd(i) from one L1 eval ======
    for (int i = 1; i < n; ++i) {
        const float tp = (float)(i - 1) * dt; // t_{i-1}

        FragU bx = make_bx(xr, tp, c, q); // [x_i; t_{i-1}; 1]
        v4f d1[4];
#pragma unroll
        for (int mt = 0; mt < 4; ++mt)
            d1[mt] = __builtin_amdgcn_mfma_f32_16x16x32_bf16(a1[mt].s, bx.s, vzero, 0, 0, 0);

        // th1b = tanh(z1 at t_{i-1}); u = om1*w1r; dh1 = om1*dt*w1t
        uint2 phb[4], pu[4], pd[4];
#pragma unroll
        for (int mt = 0; mt < 4; ++mt) {
            float t0 = ftanh(d1[mt][0]), t1 = ftanh(d1[mt][1]);
            float t2 = ftanh(d1[mt][2]), t3 = ftanh(d1[mt][3]);
            float o0 = fmaf(-t0, t0, 1.0f), o1 = fmaf(-t1, t1, 1.0f);
            float o2 = fmaf(-t2, t2, 1.0f), o3 = fmaf(-t3, t3, 1.0f);
            phb[mt].x = pkbf(t0, t1);
            phb[mt].y = pkbf(t2, t3);
            pu[mt].x = pkbf(o0 * w1rv[mt][0], o1 * w1rv[mt][1]);
            pu[mt].y = pkbf(o2 * w1rv[mt][2], o3 * w1rv[mt][3]);
            pd[mt].x = pkbf(o0 * dtw1t[mt][0], o1 * dtw1t[mt][1]);
            pd[mt].y = pkbf(o2 * dtw1t[mt][2], o3 * dtw1t[mt][3]);
        }
        FragU bhb[2], bu[2], bd[2];
        xform(phb, lA, lB, qlo, bhb);
        xform(pu, lA, lB, qlo, bu);
        xform(pd, lA, lB, qlo, bd);

        v4f z2b[4], sv[4], dz2[4];
#pragma unroll
        for (int mt = 0; mt < 4; ++mt) {
            z2b[mt] = __builtin_amdgcn_mfma_f32_16x16x32_bf16(a2[mt][0].s, bhb[0].s, vzero, 0, 0, 0);
            z2b[mt] = __builtin_amdgcn_mfma_f32_16x16x32_bf16(a2[mt][1].s, bhb[1].s, z2b[mt], 0, 0, 0);
            sv[mt] = __builtin_amdgcn_mfma_f32_16x16x32_bf16(a2[mt][0].s, bu[0].s, vzero, 0, 0, 0);
            sv[mt] = __builtin_amdgcn_mfma_f32_16x16x32_bf16(a2[mt][1].s, bu[1].s, sv[mt], 0, 0, 0);
            dz2[mt] = __builtin_amdgcn_mfma_f32_16x16x32_bf16(a2[mt][0].s, bd[0].s, vzero, 0, 0, 0);
            dz2[mt] = __builtin_amdgcn_mfma_f32_16x16x32_bf16(a2[mt][1].s, bd[1].s, dz2[mt], 0, 0, 0);
        }

        // th2b = tanh(z2b+b2): bwd L2. g += w3c*om2*s. th2f = th2b + om2*dz2.
        uint2 ph2[4];
#pragma unroll
        for (int mt = 0; mt < 4; ++mt) {
            float t0 = ftanh(z2b[mt][0] + b2v[mt][0]), t1 = ftanh(z2b[mt][1] + b2v[mt][1]);
            float t2 = ftanh(z2b[mt][2] + b2v[mt][2]), t3 = ftanh(z2b[mt][3] + b2v[mt][3]);
            float o0 = fmaf(-t0, t0, 1.0f), o1 = fmaf(-t1, t1, 1.0f);
            float o2 = fmaf(-t2, t2, 1.0f), o3 = fmaf(-t3, t3, 1.0f);
            g = fmaf(w3cv[mt][0] * o0, sv[mt][0], g);
            g = fmaf(w3cv[mt][1] * o1, sv[mt][1], g);
            g = fmaf(w3cv[mt][2] * o2, sv[mt][2], g);
            g = fmaf(w3cv[mt][3] * o3, sv[mt][3], g);
            float f0 = fmaf(o0, dz2[mt][0], t0), f1 = fmaf(o1, dz2[mt][1], t1);
            float f2 = fmaf(o2, dz2[mt][2], t2), f3 = fmaf(o3, dz2[mt][3], t3);
            ph2[mt].x = pkbf(f0, f1);
            ph2[mt].y = pkbf(f2, f3);
        }
        FragU bh2[2];
        xform(ph2, lA, lB, qlo, bh2);
        v4f d3;
        d3 = __builtin_amdgcn_mfma_f32_16x16x32_bf16(a3[0].s, bh2[0].s, vzero, 0, 0, 0);
        d3 = __builtin_amdgcn_mfma_f32_16x16x32_bf16(a3[1].s, bh2[1].s, d3, 0, 0, 0);
        if (q < 2) {
#pragma unroll
            for (int r = 0; r < 4; ++r) xr[r] = fmaf(dt, d3[r] + b3v[r], xr[r]);
        }
    }

    // ============ final bwd at (x_n, t_{n-1}) ============
    {
        const float tl = (float)(n - 1) * dt;
        FragU bx = make_bx(xr, tl, c, q);
        v4f d1[4];
#pragma unroll
        for (int mt = 0; mt < 4; ++mt)
            d1[mt] = __builtin_amdgcn_mfma_f32_16x16x32_bf16(a1[mt].s, bx.s, vzero, 0, 0, 0);
        uint2 phb[4], pu[4];
#pragma unroll
        for (int mt = 0; mt < 4; ++mt) {
            float t0 = ftanh(d1[mt][0]), t1 = ftanh(d1[mt][1]);
            float t2 = ftanh(d1[mt][2]), t3 = ftanh(d1[mt][3]);
            float o0 = fmaf(-t0, t0, 1.0f), o1 = fmaf(-t1, t1, 1.0f);
            float o2 = fmaf(-t2, t2, 1.0f), o3 = fmaf(-t3, t3, 1.0f);
            phb[mt].x = pkbf(t0, t1);
            phb[mt].y = pkbf(t2, t3);
            pu[mt].x = pkbf(o0 * w1rv[mt][0], o1 * w1rv[mt][1]);
            pu[mt].y = pkbf(o2 * w1rv[mt][2], o3 * w1rv[mt][3]);
        }
        FragU bhb[2], bu[2];
        xform(phb, lA, lB, qlo, bhb);
        xform(pu, lA, lB, qlo, bu);
        v4f z2b[4], sv[4];
#pragma unroll
        for (int mt = 0; mt < 4; ++mt) {
            z2b[mt] = __builtin_amdgcn_mfma_f32_16x16x32_bf16(a2[mt][0].s, bhb[0].s, vzero, 0, 0, 0);
            z2b[mt] = __builtin_amdgcn_mfma_f32_16x16x32_bf16(a2[mt][1].s, bhb[1].s, z2b[mt], 0, 0, 0);
            sv[mt] = __builtin_amdgcn_mfma_f32_16x16x32_bf16(a2[mt][0].s, bu[0].s, vzero, 0, 0, 0);
            sv[mt] = __builtin_amdgcn_mfma_f32_16x16x32_bf16(a2[mt][1].s, bu[1].s, sv[mt], 0, 0, 0);
        }
#pragma unroll
        for (int mt = 0; mt < 4; ++mt)
#pragma unroll
            for (int r = 0; r < 4; ++r) {
                float th2 = ftanh(z2b[mt][r] + b2v[mt][r]);
                g = fmaf(w3cv[mt][r] * fmaf(-th2, th2, 1.0f), sv[mt][r], g);
            }
    }

    // ---- epilogue ----
    g += __shfl_xor(g, 16);
    g += __shfl_xor(g, 32);
    if (q < 2) {
        float4 st = {xr[0], xr[1], xr[2], xr[3]};
        *(float4*)(out + (size_t)(row0 + c) * 8 + 4 * q) = st;
    }
    if (q == 0) out[(size_t)rows * 8 + row0 + c] = dt * g;
}

extern "C" void kernel_launch(void* const* d_in, const int* in_sizes, int n_in,
                              void* d_out, int out_size, void* d_ws, size_t ws_size,
                              hipStream_t stream) {
    const float* x0 = (const float*)d_in[0];
    const float* W1 = (const float*)d_in[1];
    const float* b1 = (const float*)d_in[2];
    const float* W2 = (const float*)d_in[3];
    const float* b2 = (const float*)d_in[4];
    const float* W3 = (const float*)d_in[5];
    const float* b3 = (const float*)d_in[6];
    const int* ns = (const int*)d_in[7];
    float* out = (float*)d_out;
    const int rows = in_sizes[0] / 8; // 32768

    hipLaunchKernelGGL(cnf_prep, dim3(1), dim3(64), 0, stream, W1, W3);
    hipLaunchKernelGGL(cnf_fused, dim3(rows / 64), dim3(256), 0, stream,
                       x0, W1, b1, W2, b2, W3, b3, ns, out, rows);
}

// Round 10
// 246.232 us; speedup vs baseline: 41.0338x; 1.3499x over previous
//
#include <hip/hip_runtime.h>
#include <hip/hip_bf16.h>

// ContinuousNormalizingFlow: B=32768 rows, D=8, H=64, 100 Euler steps.
// R10: fused MFMA kernel with ZERO cross-lane ops in the step loop.
// Key trick: sum_k A[m][k]B[k][n] is invariant under a K-permutation applied
// to both A and B. The L1/L2 C-layout at lane(c,q) holds j=16mt+4q+r; the
// next matmul's B-frag slots at the same lane are k=32ks+8q+jj. Both sets are
// q-homogeneous, so with W2/W3 stored K-permuted (phys j = 16*(ks+2*(jj>>2))
// +4q+(jj&3)) the C->B transform is a pure register rename. L1's A-layout is
// chosen so the [x;t;1] B-frag is built from lane-local state (x duplicated
// across q-quads via row-duplicated W3; A1 zeroed on duplicate slots).
// b2/b3 folded into MFMA C-inits. bwd(i-1)+fwd(i) share one L1 eval (R9).

__device__ float g_w1r[64]; // sum_{k<8} W1[j][k]
__device__ float g_w3c[64]; // sum_d W3[d][j]

__global__ void cnf_prep(const float* __restrict__ W1, const float* __restrict__ W3) {
    int h = threadIdx.x; // 64 threads
    float s = 0.f;
#pragma unroll
    for (int k = 0; k < 8; ++k) s += W1[h * 9 + k];
    g_w1r[h] = s;
    float c = 0.f;
#pragma unroll
    for (int d = 0; d < 8; ++d) c += W3[d * 64 + h];
    g_w3c[h] = c;
}

__device__ __forceinline__ float ftanh(float x) {
    // tanh(x) = 1 - 2/(exp(2x)+1); v_exp_f32 computes 2^x, inf-safe both ends.
    float e = __builtin_amdgcn_exp2f(x * 2.885390081777926815f); // 2*log2(e)
    float r = __builtin_amdgcn_rcpf(e + 1.0f);
    return fmaf(-2.0f, r, 1.0f);
}

typedef __attribute__((ext_vector_type(8))) short v8s; // 8 bf16 (4 VGPRs)
typedef __attribute__((ext_vector_type(4))) float v4f; // MFMA C/D

union FragU {
    v8s s;
    unsigned u[4];
};

__device__ __forceinline__ unsigned pkbf(float a, float b) {
    // packed bf16 cvt; a -> low half
    __hip_bfloat162 h = __float22bfloat162_rn(float2{a, b});
    unsigned r;
    __builtin_memcpy(&r, &h, sizeof(r));
    return r;
}

// K-permutation for W2/W3 frags: slot (ks,q,jj) <- physical j.
__device__ __forceinline__ int physj(int ks, int q, int jj) {
    return 16 * (ks + 2 * (jj >> 2)) + 4 * q + (jj & 3);
}

// Rename C-fragment packs (ph[4]: per-mt {r01,r23}) into the B-frag pair.
__device__ __forceinline__ void rename(const uint2 ph[4], FragU bh[2]) {
#pragma unroll
    for (int ks = 0; ks < 2; ++ks) {
        bh[ks].u[0] = ph[ks].x;
        bh[ks].u[1] = ph[ks].y;
        bh[ks].u[2] = ph[ks + 2].x;
        bh[ks].u[3] = ph[ks + 2].y;
    }
}

__global__ __launch_bounds__(256, 2) void cnf_fused(
    const float* __restrict__ x0, const float* __restrict__ W1,
    const float* __restrict__ b1, const float* __restrict__ W2,
    const float* __restrict__ b2, const float* __restrict__ W3,
    const float* __restrict__ b3, const int* __restrict__ nsp,
    float* __restrict__ out, int rows) {
    const int tid = threadIdx.x;
    const int w = tid >> 6;
    const int lane = tid & 63;
    const int c = lane & 15;
    const int q = lane >> 4;
    const int row0 = blockIdx.x * 64 + w * 16;

    const int n = *nsp;
    const float dt = 1.0f / (float)n;

    // ---- A1: [x;t;1] layout. Slots (q,jj): q0 jj0-3 = W1[:,0:4], q0 jj4 =
    // W1[:,8] (t), q0 jj5 = b1, q1 jj0-3 = W1[:,4:8], all else 0. ----
    FragU a1[4];
#pragma unroll
    for (int mt = 0; mt < 4; ++mt) {
        const int m = 16 * mt + c;
        float f[8] = {0.f, 0.f, 0.f, 0.f, 0.f, 0.f, 0.f, 0.f};
        if (q == 0) {
#pragma unroll
            for (int jj = 0; jj < 4; ++jj) f[jj] = W1[m * 9 + jj];
            f[4] = W1[m * 9 + 8];
            f[5] = b1[m];
        } else if (q == 1) {
#pragma unroll
            for (int jj = 0; jj < 4; ++jj) f[jj] = W1[m * 9 + 4 + jj];
        }
#pragma unroll
        for (int p = 0; p < 4; ++p) a1[mt].u[p] = pkbf(f[2 * p], f[2 * p + 1]);
    }
    // ---- A2: W2 K-permuted ----
    FragU a2[4][2];
#pragma unroll
    for (int mt = 0; mt < 4; ++mt)
#pragma unroll
        for (int ks = 0; ks < 2; ++ks) {
            const int m = 16 * mt + c;
            float f[8];
#pragma unroll
            for (int jj = 0; jj < 8; ++jj) f[jj] = W2[m * 64 + physj(ks, q, jj)];
#pragma unroll
            for (int p = 0; p < 4; ++p) a2[mt][ks].u[p] = pkbf(f[2 * p], f[2 * p + 1]);
        }
    // ---- A3: W3 rows duplicated (m -> m&7), K-permuted ----
    FragU a3[2];
#pragma unroll
    for (int ks = 0; ks < 2; ++ks) {
        float f[8];
#pragma unroll
        for (int jj = 0; jj < 8; ++jj) f[jj] = W3[(c & 7) * 64 + physj(ks, q, jj)];
#pragma unroll
        for (int p = 0; p < 4; ++p) a3[ks].u[p] = pkbf(f[2 * p], f[2 * p + 1]);
    }
    // ---- per-lane constants ----
    float w3cv[4][4], w1rv[4][4], dtw1t[4][4];
    v4f vb2[4];
#pragma unroll
    for (int mt = 0; mt < 4; ++mt)
#pragma unroll
        for (int r = 0; r < 4; ++r) {
            const int j = 16 * mt + 4 * q + r;
            vb2[mt][r] = b2[j];
            w3cv[mt][r] = g_w3c[j];
            w1rv[mt][r] = g_w1r[j];
            dtw1t[mt][r] = dt * W1[j * 9 + 8];
        }
    v4f vb3;
#pragma unroll
    for (int r = 0; r < 4; ++r) vb3[r] = b3[(4 * q + r) & 7];

    // ---- x state: ALL lanes hold xr[r] = x[row0+c][(4q+r)&7] (duplicated) ----
    float xr[4];
    {
        float4 v = *(const float4*)(x0 + (size_t)(row0 + c) * 8 + 4 * (q & 1));
        xr[0] = v.x; xr[1] = v.y; xr[2] = v.z; xr[3] = v.w;
    }
    const v4f vzero = {0.f, 0.f, 0.f, 0.f};
    float g = 0.f;

    // ================= iteration 0: pure forward at (x0, t=0) =================
    {
        FragU bx;
        bx.u[0] = pkbf(xr[0], xr[1]);
        bx.u[1] = pkbf(xr[2], xr[3]);
        bx.u[2] = pkbf(0.0f, 1.0f);
        bx.u[3] = 0u;
        v4f d1[4];
#pragma unroll
        for (int mt = 0; mt < 4; ++mt)
            d1[mt] = __builtin_amdgcn_mfma_f32_16x16x32_bf16(a1[mt].s, bx.s, vzero, 0, 0, 0);
        uint2 ph[4];
#pragma unroll
        for (int mt = 0; mt < 4; ++mt) {
            float t0 = ftanh(d1[mt][0]), t1 = ftanh(d1[mt][1]);
            float t2 = ftanh(d1[mt][2]), t3 = ftanh(d1[mt][3]);
            ph[mt].x = pkbf(t0, t1);
            ph[mt].y = pkbf(t2, t3);
        }
        FragU bh[2];
        rename(ph, bh);
        v4f d2[4];
#pragma unroll
        for (int mt = 0; mt < 4; ++mt) {
            d2[mt] = __builtin_amdgcn_mfma_f32_16x16x32_bf16(a2[mt][0].s, bh[0].s, vb2[mt], 0, 0, 0);
            d2[mt] = __builtin_amdgcn_mfma_f32_16x16x32_bf16(a2[mt][1].s, bh[1].s, d2[mt], 0, 0, 0);
        }
#pragma unroll
        for (int mt = 0; mt < 4; ++mt) {
            float t0 = ftanh(d2[mt][0]), t1 = ftanh(d2[mt][1]);
            float t2 = ftanh(d2[mt][2]), t3 = ftanh(d2[mt][3]);
            ph[mt].x = pkbf(t0, t1);
            ph[mt].y = pkbf(t2, t3);
        }
        FragU bh2[2];
        rename(ph, bh2);
        v4f d3;
        d3 = __builtin_amdgcn_mfma_f32_16x16x32_bf16(a3[0].s, bh2[0].s, vb3, 0, 0, 0);
        d3 = __builtin_amdgcn_mfma_f32_16x16x32_bf16(a3[1].s, bh2[1].s, d3, 0, 0, 0);
#pragma unroll
        for (int r = 0; r < 4; ++r) xr[r] = fmaf(dt, d3[r], xr[r]);
    }

    // ====== iterations i = 1..n-1: bwd(i-1) + fwd(i) from one L1 eval ======
    for (int i = 1; i < n; ++i) {
        const float tp = (float)(i - 1) * dt; // t_{i-1}

        FragU bx; // [x_i; t_{i-1}; 1]
        bx.u[0] = pkbf(xr[0], xr[1]);
        bx.u[1] = pkbf(xr[2], xr[3]);
        bx.u[2] = pkbf(tp, 1.0f);
        bx.u[3] = 0u;
        v4f d1[4];
#pragma unroll
        for (int mt = 0; mt < 4; ++mt)
            d1[mt] = __builtin_amdgcn_mfma_f32_16x16x32_bf16(a1[mt].s, bx.s, vzero, 0, 0, 0);

        // th1b = tanh(z1 @ t_{i-1}); u = om1*w1r; dh1 = om1*dt*w1t
        uint2 phb[4], pu[4], pd[4];
#pragma unroll
        for (int mt = 0; mt < 4; ++mt) {
            float t0 = ftanh(d1[mt][0]), t1 = ftanh(d1[mt][1]);
            float t2 = ftanh(d1[mt][2]), t3 = ftanh(d1[mt][3]);
            float o0 = fmaf(-t0, t0, 1.0f), o1 = fmaf(-t1, t1, 1.0f);
            float o2 = fmaf(-t2, t2, 1.0f), o3 = fmaf(-t3, t3, 1.0f);
            phb[mt].x = pkbf(t0, t1);
            phb[mt].y = pkbf(t2, t3);
            pu[mt].x = pkbf(o0 * w1rv[mt][0], o1 * w1rv[mt][1]);
            pu[mt].y = pkbf(o2 * w1rv[mt][2], o3 * w1rv[mt][3]);
            pd[mt].x = pkbf(o0 * dtw1t[mt][0], o1 * dtw1t[mt][1]);
            pd[mt].y = pkbf(o2 * dtw1t[mt][2], o3 * dtw1t[mt][3]);
        }
        FragU bhb[2], bu[2], bd[2];
        rename(phb, bhb);
        rename(pu, bu);
        rename(pd, bd);

        v4f z2b[4], sv[4], dz2[4];
#pragma unroll
        for (int mt = 0; mt < 4; ++mt) {
            z2b[mt] = __builtin_amdgcn_mfma_f32_16x16x32_bf16(a2[mt][0].s, bhb[0].s, vb2[mt], 0, 0, 0);
            z2b[mt] = __builtin_amdgcn_mfma_f32_16x16x32_bf16(a2[mt][1].s, bhb[1].s, z2b[mt], 0, 0, 0);
            sv[mt] = __builtin_amdgcn_mfma_f32_16x16x32_bf16(a2[mt][0].s, bu[0].s, vzero, 0, 0, 0);
            sv[mt] = __builtin_amdgcn_mfma_f32_16x16x32_bf16(a2[mt][1].s, bu[1].s, sv[mt], 0, 0, 0);
            dz2[mt] = __builtin_amdgcn_mfma_f32_16x16x32_bf16(a2[mt][0].s, bd[0].s, vzero, 0, 0, 0);
            dz2[mt] = __builtin_amdgcn_mfma_f32_16x16x32_bf16(a2[mt][1].s, bd[1].s, dz2[mt], 0, 0, 0);
        }

        // th2b = tanh(z2b) (bias in C-init). g += w3c*om2*s. th2f = th2b+om2*dz2.
        uint2 ph2[4];
#pragma unroll
        for (int mt = 0; mt < 4; ++mt) {
            float t0 = ftanh(z2b[mt][0]), t1 = ftanh(z2b[mt][1]);
            float t2 = ftanh(z2b[mt][2]), t3 = ftanh(z2b[mt][3]);
            float o0 = fmaf(-t0, t0, 1.0f), o1 = fmaf(-t1, t1, 1.0f);
            float o2 = fmaf(-t2, t2, 1.0f), o3 = fmaf(-t3, t3, 1.0f);
            g = fmaf(w3cv[mt][0] * o0, sv[mt][0], g);
            g = fmaf(w3cv[mt][1] * o1, sv[mt][1], g);
            g = fmaf(w3cv[mt][2] * o2, sv[mt][2], g);
            g = fmaf(w3cv[mt][3] * o3, sv[mt][3], g);
            float f0 = fmaf(o0, dz2[mt][0], t0), f1 = fmaf(o1, dz2[mt][1], t1);
            float f2 = fmaf(o2, dz2[mt][2], t2), f3 = fmaf(o3, dz2[mt][3], t3);
            ph2[mt].x = pkbf(f0, f1);
            ph2[mt].y = pkbf(f2, f3);
        }
        FragU bh2[2];
        rename(ph2, bh2);
        v4f d3;
        d3 = __builtin_amdgcn_mfma_f32_16x16x32_bf16(a3[0].s, bh2[0].s, vb3, 0, 0, 0);
        d3 = __builtin_amdgcn_mfma_f32_16x16x32_bf16(a3[1].s, bh2[1].s, d3, 0, 0, 0);
#pragma unroll
        for (int r = 0; r < 4; ++r) xr[r] = fmaf(dt, d3[r], xr[r]);
    }

    // ============ final bwd at (x_n, t_{n-1}) ============
    {
        const float tl = (float)(n - 1) * dt;
        FragU bx;
        bx.u[0] = pkbf(xr[0], xr[1]);
        bx.u[1] = pkbf(xr[2], xr[3]);
        bx.u[2] = pkbf(tl, 1.0f);
        bx.u[3] = 0u;
        v4f d1[4];
#pragma unroll
        for (int mt = 0; mt < 4; ++mt)
            d1[mt] = __builtin_amdgcn_mfma_f32_16x16x32_bf16(a1[mt].s, bx.s, vzero, 0, 0, 0);
        uint2 phb[4], pu[4];
#pragma unroll
        for (int mt = 0; mt < 4; ++mt) {
            float t0 = ftanh(d1[mt][0]), t1 = ftanh(d1[mt][1]);
            float t2 = ftanh(d1[mt][2]), t3 = ftanh(d1[mt][3]);
            float o0 = fmaf(-t0, t0, 1.0f), o1 = fmaf(-t1, t1, 1.0f);
            float o2 = fmaf(-t2, t2, 1.0f), o3 = fmaf(-t3, t3, 1.0f);
            phb[mt].x = pkbf(t0, t1);
            phb[mt].y = pkbf(t2, t3);
            pu[mt].x = pkbf(o0 * w1rv[mt][0], o1 * w1rv[mt][1]);
            pu[mt].y = pkbf(o2 * w1rv[mt][2], o3 * w1rv[mt][3]);
        }
        FragU bhb[2], bu[2];
        rename(phb, bhb);
        rename(pu, bu);
        v4f z2b[4], sv[4];
#pragma unroll
        for (int mt = 0; mt < 4; ++mt) {
            z2b[mt] = __builtin_amdgcn_mfma_f32_16x16x32_bf16(a2[mt][0].s, bhb[0].s, vb2[mt], 0, 0, 0);
            z2b[mt] = __builtin_amdgcn_mfma_f32_16x16x32_bf16(a2[mt][1].s, bhb[1].s, z2b[mt], 0, 0, 0);
            sv[mt] = __builtin_amdgcn_mfma_f32_16x16x32_bf16(a2[mt][0].s, bu[0].s, vzero, 0, 0, 0);
            sv[mt] = __builtin_amdgcn_mfma_f32_16x16x32_bf16(a2[mt][1].s, bu[1].s, sv[mt], 0, 0, 0);
        }
#pragma unroll
        for (int mt = 0; mt < 4; ++mt)
#pragma unroll
            for (int r = 0; r < 4; ++r) {
                float th2 = ftanh(z2b[mt][r]);
                g = fmaf(w3cv[mt][r] * fmaf(-th2, th2, 1.0f), sv[mt][r], g);
            }
    }

    // ---- epilogue ----
    g += __shfl_xor(g, 16);
    g += __shfl_xor(g, 32);
    if (q < 2) {
        float4 st = {xr[0], xr[1], xr[2], xr[3]};
        *(float4*)(out + (size_t)(row0 + c) * 8 + 4 * q) = st;
    }
    if (q == 0) out[(size_t)rows * 8 + row0 + c] = dt * g;
}

extern "C" void kernel_launch(void* const* d_in, const int* in_sizes, int n_in,
                              void* d_out, int out_size, void* d_ws, size_t ws_size,
                              hipStream_t stream) {
    const float* x0 = (const float*)d_in[0];
    const float* W1 = (const float*)d_in[1];
    const float* b1 = (const float*)d_in[2];
    const float* W2 = (const float*)d_in[3];
    const float* b2 = (const float*)d_in[4];
    const float* W3 = (const float*)d_in[5];
    const float* b3 = (const float*)d_in[6];
    const int* ns = (const int*)d_in[7];
    float* out = (float*)d_out;
    const int rows = in_sizes[0] / 8; // 32768

    hipLaunchKernelGGL(cnf_prep, dim3(1), dim3(64), 0, stream, W1, W3);
    hipLaunchKernelGGL(cnf_fused, dim3(rows / 64), dim3(256), 0, stream,
                       x0, W1, b1, W2, b2, W3, b3, ns, out, rows);
}

// Round 11
// 226.746 us; speedup vs baseline: 44.5601x; 1.0859x over previous
//
#include <hip/hip_runtime.h>

// ContinuousNormalizingFlow: B=32768 rows, D=8, H=64, 100 Euler steps.
// R11 = R10 (zero cross-lane step loop, K-permutation renames) plus:
//  - sv/dz2 operands folded into pre-scaled weight copies a2u=W2*w1r,
//    a2d=W2*(dt*w1t): only om1 is packed (kills 32 mul + 8 packs/step)
//  - 3-instr bf16 pair pack: round-half-up add + v_perm_b32
//  - float2 packed math (v_pk_fma_f32) for om/g/th2f elementwise blocks

__device__ float g_w1r[64]; // sum_{k<8} W1[j][k]
__device__ float g_w3c[64]; // sum_d W3[d][j]

__global__ void cnf_prep(const float* __restrict__ W1, const float* __restrict__ W3) {
    int h = threadIdx.x; // 64 threads
    float s = 0.f;
#pragma unroll
    for (int k = 0; k < 8; ++k) s += W1[h * 9 + k];
    g_w1r[h] = s;
    float c = 0.f;
#pragma unroll
    for (int d = 0; d < 8; ++d) c += W3[d * 64 + h];
    g_w3c[h] = c;
}

__device__ __forceinline__ float ftanh(float x) {
    // tanh(x) = 1 - 2/(exp(2x)+1); v_exp_f32 computes 2^x, inf-safe both ends.
    float e = __builtin_amdgcn_exp2f(x * 2.885390081777926815f); // 2*log2(e)
    float r = __builtin_amdgcn_rcpf(e + 1.0f);
    return fmaf(-2.0f, r, 1.0f);
}

typedef __attribute__((ext_vector_type(8))) short v8s; // 8 bf16 (4 VGPRs)
typedef __attribute__((ext_vector_type(4))) float v4f; // MFMA C/D
typedef __attribute__((ext_vector_type(2))) float v2f; // packed fp32 pair

union FragU {
    v8s s;
    unsigned u[4];
};

// bf16 pair pack: round-half-up (+0x8000) then splice high halves.
// 3 VALU: v_add, v_add, v_perm_b32.  a -> low half.
__device__ __forceinline__ unsigned pkbf(float a, float b) {
    unsigned ua = __builtin_bit_cast(unsigned, a) + 0x8000u;
    unsigned ub = __builtin_bit_cast(unsigned, b) + 0x8000u;
    return __builtin_amdgcn_perm(ub, ua, 0x07060302u);
}
__device__ __forceinline__ unsigned pkbf2(v2f v) { return pkbf(v.x, v.y); }

// K-permutation for W2/W3 frags: slot (ks,q,jj) <- physical j.
__device__ __forceinline__ int physj(int ks, int q, int jj) {
    return 16 * (ks + 2 * (jj >> 2)) + 4 * q + (jj & 3);
}

// Rename C-fragment packs (ph[4]: per-mt {r01,r23}) into the B-frag pair.
__device__ __forceinline__ void rename(const uint2 ph[4], FragU bh[2]) {
#pragma unroll
    for (int ks = 0; ks < 2; ++ks) {
        bh[ks].u[0] = ph[ks].x;
        bh[ks].u[1] = ph[ks].y;
        bh[ks].u[2] = ph[ks + 2].x;
        bh[ks].u[3] = ph[ks + 2].y;
    }
}

__global__ __launch_bounds__(256, 2) void cnf_fused(
    const float* __restrict__ x0, const float* __restrict__ W1,
    const float* __restrict__ b1, const float* __restrict__ W2,
    const float* __restrict__ b2, const float* __restrict__ W3,
    const float* __restrict__ b3, const int* __restrict__ nsp,
    float* __restrict__ out, int rows) {
    const int tid = threadIdx.x;
    const int w = tid >> 6;
    const int lane = tid & 63;
    const int c = lane & 15;
    const int q = lane >> 4;
    const int row0 = blockIdx.x * 64 + w * 16;

    const int n = *nsp;
    const float dt = 1.0f / (float)n;

    // ---- A1: [x;t;1] layout. Slots (q,jj): q0 jj0-3 = W1[:,0:4], q0 jj4 =
    // W1[:,8] (t), q0 jj5 = b1, q1 jj0-3 = W1[:,4:8], all else 0. ----
    FragU a1[4];
#pragma unroll
    for (int mt = 0; mt < 4; ++mt) {
        const int m = 16 * mt + c;
        float f[8] = {0.f, 0.f, 0.f, 0.f, 0.f, 0.f, 0.f, 0.f};
        if (q == 0) {
#pragma unroll
            for (int jj = 0; jj < 4; ++jj) f[jj] = W1[m * 9 + jj];
            f[4] = W1[m * 9 + 8];
            f[5] = b1[m];
        } else if (q == 1) {
#pragma unroll
            for (int jj = 0; jj < 4; ++jj) f[jj] = W1[m * 9 + 4 + jj];
        }
#pragma unroll
        for (int p = 0; p < 4; ++p) a1[mt].u[p] = pkbf(f[2 * p], f[2 * p + 1]);
    }
    // ---- A2: W2 K-permuted; a2u = W2*w1r[h]; a2d = W2*(dt*w1t[h]) ----
    FragU a2[4][2], a2u[4][2], a2d[4][2];
#pragma unroll
    for (int mt = 0; mt < 4; ++mt)
#pragma unroll
        for (int ks = 0; ks < 2; ++ks) {
            const int m = 16 * mt + c;
            float f[8], fu[8], fd[8];
#pragma unroll
            for (int jj = 0; jj < 8; ++jj) {
                const int pj = physj(ks, q, jj);
                const float wv = W2[m * 64 + pj];
                f[jj] = wv;
                fu[jj] = wv * g_w1r[pj];
                fd[jj] = wv * (dt * W1[pj * 9 + 8]);
            }
#pragma unroll
            for (int p = 0; p < 4; ++p) {
                a2[mt][ks].u[p] = pkbf(f[2 * p], f[2 * p + 1]);
                a2u[mt][ks].u[p] = pkbf(fu[2 * p], fu[2 * p + 1]);
                a2d[mt][ks].u[p] = pkbf(fd[2 * p], fd[2 * p + 1]);
            }
        }
    // ---- A3: W3 rows duplicated (m -> m&7), K-permuted ----
    FragU a3[2];
#pragma unroll
    for (int ks = 0; ks < 2; ++ks) {
        float f[8];
#pragma unroll
        for (int jj = 0; jj < 8; ++jj) f[jj] = W3[(c & 7) * 64 + physj(ks, q, jj)];
#pragma unroll
        for (int p = 0; p < 4; ++p) a3[ks].u[p] = pkbf(f[2 * p], f[2 * p + 1]);
    }
    // ---- per-lane constants ----
    v2f w3c01[4], w3c23[4];
    v4f vb2[4];
#pragma unroll
    for (int mt = 0; mt < 4; ++mt) {
        const int j0 = 16 * mt + 4 * q;
        vb2[mt][0] = b2[j0]; vb2[mt][1] = b2[j0 + 1];
        vb2[mt][2] = b2[j0 + 2]; vb2[mt][3] = b2[j0 + 3];
        w3c01[mt] = v2f{g_w3c[j0], g_w3c[j0 + 1]};
        w3c23[mt] = v2f{g_w3c[j0 + 2], g_w3c[j0 + 3]};
    }
    v4f vb3;
#pragma unroll
    for (int r = 0; r < 4; ++r) vb3[r] = b3[(4 * q + r) & 7];

    // ---- x state: ALL lanes hold xr[r] = x[row0+c][(4q+r)&7] (duplicated) ----
    float xr[4];
    {
        float4 v = *(const float4*)(x0 + (size_t)(row0 + c) * 8 + 4 * (q & 1));
        xr[0] = v.x; xr[1] = v.y; xr[2] = v.z; xr[3] = v.w;
    }
    const v4f vzero = {0.f, 0.f, 0.f, 0.f};
    v2f gv = {0.f, 0.f};

    // ================= iteration 0: pure forward at (x0, t=0) =================
    {
        FragU bx;
        bx.u[0] = pkbf(xr[0], xr[1]);
        bx.u[1] = pkbf(xr[2], xr[3]);
        bx.u[2] = pkbf(0.0f, 1.0f);
        bx.u[3] = 0u;
        v4f d1[4];
#pragma unroll
        for (int mt = 0; mt < 4; ++mt)
            d1[mt] = __builtin_amdgcn_mfma_f32_16x16x32_bf16(a1[mt].s, bx.s, vzero, 0, 0, 0);
        uint2 ph[4];
#pragma unroll
        for (int mt = 0; mt < 4; ++mt) {
            ph[mt].x = pkbf(ftanh(d1[mt][0]), ftanh(d1[mt][1]));
            ph[mt].y = pkbf(ftanh(d1[mt][2]), ftanh(d1[mt][3]));
        }
        FragU bh[2];
        rename(ph, bh);
        v4f d2[4];
#pragma unroll
        for (int mt = 0; mt < 4; ++mt) {
            d2[mt] = __builtin_amdgcn_mfma_f32_16x16x32_bf16(a2[mt][0].s, bh[0].s, vb2[mt], 0, 0, 0);
            d2[mt] = __builtin_amdgcn_mfma_f32_16x16x32_bf16(a2[mt][1].s, bh[1].s, d2[mt], 0, 0, 0);
        }
#pragma unroll
        for (int mt = 0; mt < 4; ++mt) {
            ph[mt].x = pkbf(ftanh(d2[mt][0]), ftanh(d2[mt][1]));
            ph[mt].y = pkbf(ftanh(d2[mt][2]), ftanh(d2[mt][3]));
        }
        FragU bh2[2];
        rename(ph, bh2);
        v4f d3;
        d3 = __builtin_amdgcn_mfma_f32_16x16x32_bf16(a3[0].s, bh2[0].s, vb3, 0, 0, 0);
        d3 = __builtin_amdgcn_mfma_f32_16x16x32_bf16(a3[1].s, bh2[1].s, d3, 0, 0, 0);
#pragma unroll
        for (int r = 0; r < 4; ++r) xr[r] = fmaf(dt, d3[r], xr[r]);
    }

    // ====== iterations i = 1..n-1: bwd(i-1) + fwd(i) from one L1 eval ======
    float tp = 0.0f; // t_{i-1}
    for (int i = 1; i < n; ++i) {
        FragU bx; // [x_i; t_{i-1}; 1]
        bx.u[0] = pkbf(xr[0], xr[1]);
        bx.u[1] = pkbf(xr[2], xr[3]);
        bx.u[2] = pkbf(tp, 1.0f);
        bx.u[3] = 0u;
        tp += dt;
        v4f d1[4];
#pragma unroll
        for (int mt = 0; mt < 4; ++mt)
            d1[mt] = __builtin_amdgcn_mfma_f32_16x16x32_bf16(a1[mt].s, bx.s, vzero, 0, 0, 0);

        // th1b = tanh(z1 @ t_{i-1}); om1 = 1 - th1b^2 (packed math)
        uint2 phb[4], pom[4];
#pragma unroll
        for (int mt = 0; mt < 4; ++mt) {
            v2f th01 = {ftanh(d1[mt][0]), ftanh(d1[mt][1])};
            v2f th23 = {ftanh(d1[mt][2]), ftanh(d1[mt][3])};
            v2f om01 = v2f{1.f, 1.f} - th01 * th01;
            v2f om23 = v2f{1.f, 1.f} - th23 * th23;
            phb[mt].x = pkbf2(th01);
            phb[mt].y = pkbf2(th23);
            pom[mt].x = pkbf2(om01);
            pom[mt].y = pkbf2(om23);
        }
        FragU bhb[2], bo[2];
        rename(phb, bhb);
        rename(pom, bo);

        v4f z2b[4], sv[4], dz2[4];
#pragma unroll
        for (int mt = 0; mt < 4; ++mt) {
            z2b[mt] = __builtin_amdgcn_mfma_f32_16x16x32_bf16(a2[mt][0].s, bhb[0].s, vb2[mt], 0, 0, 0);
            z2b[mt] = __builtin_amdgcn_mfma_f32_16x16x32_bf16(a2[mt][1].s, bhb[1].s, z2b[mt], 0, 0, 0);
            sv[mt] = __builtin_amdgcn_mfma_f32_16x16x32_bf16(a2u[mt][0].s, bo[0].s, vzero, 0, 0, 0);
            sv[mt] = __builtin_amdgcn_mfma_f32_16x16x32_bf16(a2u[mt][1].s, bo[1].s, sv[mt], 0, 0, 0);
            dz2[mt] = __builtin_amdgcn_mfma_f32_16x16x32_bf16(a2d[mt][0].s, bo[0].s, vzero, 0, 0, 0);
            dz2[mt] = __builtin_amdgcn_mfma_f32_16x16x32_bf16(a2d[mt][1].s, bo[1].s, dz2[mt], 0, 0, 0);
        }

        // th2b = tanh(z2b) (bias in C-init). g += w3c*om2*sv. th2f = th2b+om2*dz2.
        uint2 ph2[4];
#pragma unroll
        for (int mt = 0; mt < 4; ++mt) {
            v2f th01 = {ftanh(z2b[mt][0]), ftanh(z2b[mt][1])};
            v2f th23 = {ftanh(z2b[mt][2]), ftanh(z2b[mt][3])};
            v2f om01 = v2f{1.f, 1.f} - th01 * th01;
            v2f om23 = v2f{1.f, 1.f} - th23 * th23;
            gv += (w3c01[mt] * om01) * v2f{sv[mt][0], sv[mt][1]};
            gv += (w3c23[mt] * om23) * v2f{sv[mt][2], sv[mt][3]};
            v2f tf01 = om01 * v2f{dz2[mt][0], dz2[mt][1]} + th01;
            v2f tf23 = om23 * v2f{dz2[mt][2], dz2[mt][3]} + th23;
            ph2[mt].x = pkbf2(tf01);
            ph2[mt].y = pkbf2(tf23);
        }
        FragU bh2[2];
        rename(ph2, bh2);
        v4f d3;
        d3 = __builtin_amdgcn_mfma_f32_16x16x32_bf16(a3[0].s, bh2[0].s, vb3, 0, 0, 0);
        d3 = __builtin_amdgcn_mfma_f32_16x16x32_bf16(a3[1].s, bh2[1].s, d3, 0, 0, 0);
#pragma unroll
        for (int r = 0; r < 4; ++r) xr[r] = fmaf(dt, d3[r], xr[r]);
    }

    // ============ final bwd at (x_n, t_{n-1}) ============
    {
        FragU bx;
        bx.u[0] = pkbf(xr[0], xr[1]);
        bx.u[1] = pkbf(xr[2], xr[3]);
        bx.u[2] = pkbf(tp, 1.0f); // tp == (n-1)*dt
        bx.u[3] = 0u;
        v4f d1[4];
#pragma unroll
        for (int mt = 0; mt < 4; ++mt)
            d1[mt] = __builtin_amdgcn_mfma_f32_16x16x32_bf16(a1[mt].s, bx.s, vzero, 0, 0, 0);
        uint2 phb[4], pom[4];
#pragma unroll
        for (int mt = 0; mt < 4; ++mt) {
            v2f th01 = {ftanh(d1[mt][0]), ftanh(d1[mt][1])};
            v2f th23 = {ftanh(d1[mt][2]), ftanh(d1[mt][3])};
            v2f om01 = v2f{1.f, 1.f} - th01 * th01;
            v2f om23 = v2f{1.f, 1.f} - th23 * th23;
            phb[mt].x = pkbf2(th01);
            phb[mt].y = pkbf2(th23);
            pom[mt].x = pkbf2(om01);
            pom[mt].y = pkbf2(om23);
        }
        FragU bhb[2], bo[2];
        rename(phb, bhb);
        rename(pom, bo);
        v4f z2b[4], sv[4];
#pragma unroll
        for (int mt = 0; mt < 4; ++mt) {
            z2b[mt] = __builtin_amdgcn_mfma_f32_16x16x32_bf16(a2[mt][0].s, bhb[0].s, vb2[mt], 0, 0, 0);
            z2b[mt] = __builtin_amdgcn_mfma_f32_16x16x32_bf16(a2[mt][1].s, bhb[1].s, z2b[mt], 0, 0, 0);
            sv[mt] = __builtin_amdgcn_mfma_f32_16x16x32_bf16(a2u[mt][0].s, bo[0].s, vzero, 0, 0, 0);
            sv[mt] = __builtin_amdgcn_mfma_f32_16x16x32_bf16(a2u[mt][1].s, bo[1].s, sv[mt], 0, 0, 0);
        }
#pragma unroll
        for (int mt = 0; mt < 4; ++mt) {
            v2f th01 = {ftanh(z2b[mt][0]), ftanh(z2b[mt][1])};
            v2f th23 = {ftanh(z2b[mt][2]), ftanh(z2b[mt][3])};
            v2f om01 = v2f{1.f, 1.f} - th01 * th01;
            v2f om23 = v2f{1.f, 1.f} - th23 * th23;
            gv += (w3c01[mt] * om01) * v2f{sv[mt][0], sv[mt][1]};
            gv += (w3c23[mt] * om23) * v2f{sv[mt][2], sv[mt][3]};
        }
    }

    // ---- epilogue ----
    float g = gv.x + gv.y;
    g += __shfl_xor(g, 16);
    g += __shfl_xor(g, 32);
    if (q < 2) {
        float4 st = {xr[0], xr[1], xr[2], xr[3]};
        *(float4*)(out + (size_t)(row0 + c) * 8 + 4 * q) = st;
    }
    if (q == 0) out[(size_t)rows * 8 + row0 + c] = dt * g;
}

extern "C" void kernel_launch(void* const* d_in, const int* in_sizes, int n_in,
                              void* d_out, int out_size, void* d_ws, size_t ws_size,
                              hipStream_t stream) {
    const float* x0 = (const float*)d_in[0];
    const float* W1 = (const float*)d_in[1];
    const float* b1 = (const float*)d_in[2];
    const float* W2 = (const float*)d_in[3];
    const float* b2 = (const float*)d_in[4];
    const float* W3 = (const float*)d_in[5];
    const float* b3 = (const float*)d_in[6];
    const int* ns = (const int*)d_in[7];
    float* out = (float*)d_out;
    const int rows = in_sizes[0] / 8; // 32768

    hipLaunchKernelGGL(cnf_prep, dim3(1), dim3(64), 0, stream, W1, W3);
    hipLaunchKernelGGL(cnf_fused, dim3(rows / 64), dim3(256), 0, stream,
                       x0, W1, b1, W2, b2, W3, b3, ns, out, rows);
}

// Round 13
// 204.612 us; speedup vs baseline: 49.3804x; 1.1082x over previous
//
#include <hip/hip_runtime.h>

// ContinuousNormalizingFlow: B=32768 rows, D=8, H=64, 100 Euler steps.
// R13 = R11 (zero cross-lane loop, K-perm renames, prescaled sv/dz2 weights)
// with: all frags in f16 (mfma_*_f16; packs via 1-instr v_cvt_pkrtz),
// 2*log2(e) folded into A1/A2/b1/b2 (tanh loses its mul), w3c folded into
// the sv weights (g-accum is a bare pk_fma).

#define TSCALE 2.885390081777926815f // 2*log2(e)

__device__ float g_w1r[64]; // sum_{k<8} W1[j][k]
__device__ float g_w3c[64]; // sum_d W3[d][j]

__global__ void cnf_prep(const float* __restrict__ W1, const float* __restrict__ W3) {
    int h = threadIdx.x; // 64 threads
    float s = 0.f;
#pragma unroll
    for (int k = 0; k < 8; ++k) s += W1[h * 9 + k];
    g_w1r[h] = s;
    float c = 0.f;
#pragma unroll
    for (int d = 0; d < 8; ++d) c += W3[d * 64 + h];
    g_w3c[h] = c;
}

// tanh from PRE-SCALED z (z = 2*log2e*x): 1 - 2/(2^z + 1). inf-safe.
__device__ __forceinline__ float ftanh_s(float z) {
    float e = __builtin_amdgcn_exp2f(z);
    float r = __builtin_amdgcn_rcpf(e + 1.0f);
    return fmaf(-2.0f, r, 1.0f);
}

typedef __attribute__((ext_vector_type(8))) _Float16 v8h; // 8 f16 (4 VGPRs)
typedef __attribute__((ext_vector_type(2))) __fp16 v2fp; // cvt_pkrtz result
typedef __attribute__((ext_vector_type(4))) float v4f;   // MFMA C/D
typedef __attribute__((ext_vector_type(2))) float v2f;   // packed fp32 pair

union FragU {
    v8h h;
    unsigned u[4];
};

// f16 pair pack: single v_cvt_pkrtz_f16_f32. a -> low half.
__device__ __forceinline__ unsigned pk16(float a, float b) {
    v2fp t = __builtin_amdgcn_cvt_pkrtz(a, b);
    return __builtin_bit_cast(unsigned, t);
}
__device__ __forceinline__ unsigned pk16v(v2f v) { return pk16(v.x, v.y); }

// K-permutation for W2/W3 frags: slot (ks,q,jj) <- physical j.
__device__ __forceinline__ int physj(int ks, int q, int jj) {
    return 16 * (ks + 2 * (jj >> 2)) + 4 * q + (jj & 3);
}

// Rename C-fragment packs (ph[4]: per-mt {r01,r23}) into the B-frag pair.
__device__ __forceinline__ void rename(const uint2 ph[4], FragU bh[2]) {
#pragma unroll
    for (int ks = 0; ks < 2; ++ks) {
        bh[ks].u[0] = ph[ks].x;
        bh[ks].u[1] = ph[ks].y;
        bh[ks].u[2] = ph[ks + 2].x;
        bh[ks].u[3] = ph[ks + 2].y;
    }
}

__global__ __launch_bounds__(256, 2) void cnf_fused(
    const float* __restrict__ x0, const float* __restrict__ W1,
    const float* __restrict__ b1, const float* __restrict__ W2,
    const float* __restrict__ b2, const float* __restrict__ W3,
    const float* __restrict__ b3, const int* __restrict__ nsp,
    float* __restrict__ out, int rows) {
    const int tid = threadIdx.x;
    const int w = tid >> 6;
    const int lane = tid & 63;
    const int c = lane & 15;
    const int q = lane >> 4;
    const int row0 = blockIdx.x * 64 + w * 16;

    const int n = *nsp;
    const float dt = 1.0f / (float)n;

    // ---- A1 (x TSCALE): [x;t;1] layout. q0 jj0-3 = W1[:,0:4], q0 jj4 =
    // W1[:,8] (t), q0 jj5 = b1, q1 jj0-3 = W1[:,4:8], all else 0. ----
    FragU a1[4];
#pragma unroll
    for (int mt = 0; mt < 4; ++mt) {
        const int m = 16 * mt + c;
        float f[8] = {0.f, 0.f, 0.f, 0.f, 0.f, 0.f, 0.f, 0.f};
        if (q == 0) {
#pragma unroll
            for (int jj = 0; jj < 4; ++jj) f[jj] = TSCALE * W1[m * 9 + jj];
            f[4] = TSCALE * W1[m * 9 + 8];
            f[5] = TSCALE * b1[m];
        } else if (q == 1) {
#pragma unroll
            for (int jj = 0; jj < 4; ++jj) f[jj] = TSCALE * W1[m * 9 + 4 + jj];
        }
#pragma unroll
        for (int p = 0; p < 4; ++p) a1[mt].u[p] = pk16(f[2 * p], f[2 * p + 1]);
    }
    // ---- A2 (x TSCALE) K-perm; a2g = w3c[m]*W2*w1r[h]; a2d = W2*(dt*w1t[h]) ----
    FragU a2[4][2], a2g[4][2], a2d[4][2];
#pragma unroll
    for (int mt = 0; mt < 4; ++mt)
#pragma unroll
        for (int ks = 0; ks < 2; ++ks) {
            const int m = 16 * mt + c;
            const float w3cm = g_w3c[m];
            float f[8], fg[8], fd[8];
#pragma unroll
            for (int jj = 0; jj < 8; ++jj) {
                const int pj = physj(ks, q, jj);
                const float wv = W2[m * 64 + pj];
                f[jj] = TSCALE * wv;
                fg[jj] = w3cm * wv * g_w1r[pj];
                fd[jj] = wv * (dt * W1[pj * 9 + 8]);
            }
#pragma unroll
            for (int p = 0; p < 4; ++p) {
                a2[mt][ks].u[p] = pk16(f[2 * p], f[2 * p + 1]);
                a2g[mt][ks].u[p] = pk16(fg[2 * p], fg[2 * p + 1]);
                a2d[mt][ks].u[p] = pk16(fd[2 * p], fd[2 * p + 1]);
            }
        }
    // ---- A3: W3 rows duplicated (m -> m&7), K-permuted ----
    FragU a3[2];
#pragma unroll
    for (int ks = 0; ks < 2; ++ks) {
        float f[8];
#pragma unroll
        for (int jj = 0; jj < 8; ++jj) f[jj] = W3[(c & 7) * 64 + physj(ks, q, jj)];
#pragma unroll
        for (int p = 0; p < 4; ++p) a3[ks].u[p] = pk16(f[2 * p], f[2 * p + 1]);
    }
    // ---- per-lane constants ----
    v4f vb2[4]; // x TSCALE (C-init for scaled z2)
#pragma unroll
    for (int mt = 0; mt < 4; ++mt) {
        const int j0 = 16 * mt + 4 * q;
        vb2[mt][0] = TSCALE * b2[j0]; vb2[mt][1] = TSCALE * b2[j0 + 1];
        vb2[mt][2] = TSCALE * b2[j0 + 2]; vb2[mt][3] = TSCALE * b2[j0 + 3];
    }
    v4f vb3;
#pragma unroll
    for (int r = 0; r < 4; ++r) vb3[r] = b3[(4 * q + r) & 7];

    // ---- x state: ALL lanes hold xr[r] = x[row0+c][(4q+r)&7] (duplicated) ----
    float xr[4];
    {
        float4 v = *(const float4*)(x0 + (size_t)(row0 + c) * 8 + 4 * (q & 1));
        xr[0] = v.x; xr[1] = v.y; xr[2] = v.z; xr[3] = v.w;
    }
    const v4f vzero = {0.f, 0.f, 0.f, 0.f};
    v2f gv = {0.f, 0.f};

    // ================= iteration 0: pure forward at (x0, t=0) =================
    {
        FragU bx;
        bx.u[0] = pk16(xr[0], xr[1]);
        bx.u[1] = pk16(xr[2], xr[3]);
        bx.u[2] = pk16(0.0f, 1.0f);
        bx.u[3] = 0u;
        v4f d1[4];
#pragma unroll
        for (int mt = 0; mt < 4; ++mt)
            d1[mt] = __builtin_amdgcn_mfma_f32_16x16x32_f16(a1[mt].h, bx.h, vzero, 0, 0, 0);
        uint2 ph[4];
#pragma unroll
        for (int mt = 0; mt < 4; ++mt) {
            ph[mt].x = pk16(ftanh_s(d1[mt][0]), ftanh_s(d1[mt][1]));
            ph[mt].y = pk16(ftanh_s(d1[mt][2]), ftanh_s(d1[mt][3]));
        }
        FragU bh[2];
        rename(ph, bh);
        v4f d2[4];
#pragma unroll
        for (int mt = 0; mt < 4; ++mt) {
            d2[mt] = __builtin_amdgcn_mfma_f32_16x16x32_f16(a2[mt][0].h, bh[0].h, vb2[mt], 0, 0, 0);
            d2[mt] = __builtin_amdgcn_mfma_f32_16x16x32_f16(a2[mt][1].h, bh[1].h, d2[mt], 0, 0, 0);
        }
#pragma unroll
        for (int mt = 0; mt < 4; ++mt) {
            ph[mt].x = pk16(ftanh_s(d2[mt][0]), ftanh_s(d2[mt][1]));
            ph[mt].y = pk16(ftanh_s(d2[mt][2]), ftanh_s(d2[mt][3]));
        }
        FragU bh2[2];
        rename(ph, bh2);
        v4f d3;
        d3 = __builtin_amdgcn_mfma_f32_16x16x32_f16(a3[0].h, bh2[0].h, vb3, 0, 0, 0);
        d3 = __builtin_amdgcn_mfma_f32_16x16x32_f16(a3[1].h, bh2[1].h, d3, 0, 0, 0);
#pragma unroll
        for (int r = 0; r < 4; ++r) xr[r] = fmaf(dt, d3[r], xr[r]);
    }

    // ====== iterations i = 1..n-1: bwd(i-1) + fwd(i) from one L1 eval ======
    float tp = 0.0f; // t_{i-1}
    for (int i = 1; i < n; ++i) {
        FragU bx; // [x_i; t_{i-1}; 1]
        bx.u[0] = pk16(xr[0], xr[1]);
        bx.u[1] = pk16(xr[2], xr[3]);
        bx.u[2] = pk16(tp, 1.0f);
        bx.u[3] = 0u;
        tp += dt;
        v4f d1[4];
#pragma unroll
        for (int mt = 0; mt < 4; ++mt)
            d1[mt] = __builtin_amdgcn_mfma_f32_16x16x32_f16(a1[mt].h, bx.h, vzero, 0, 0, 0);

        // th1b = tanh(z1 @ t_{i-1}); om1 = 1 - th1b^2 (packed math)
        uint2 phb[4], pom[4];
#pragma unroll
        for (int mt = 0; mt < 4; ++mt) {
            v2f th01 = {ftanh_s(d1[mt][0]), ftanh_s(d1[mt][1])};
            v2f th23 = {ftanh_s(d1[mt][2]), ftanh_s(d1[mt][3])};
            v2f om01 = v2f{1.f, 1.f} - th01 * th01;
            v2f om23 = v2f{1.f, 1.f} - th23 * th23;
            phb[mt].x = pk16v(th01);
            phb[mt].y = pk16v(th23);
            pom[mt].x = pk16v(om01);
            pom[mt].y = pk16v(om23);
        }
        FragU bhb[2], bo[2];
        rename(phb, bhb);
        rename(pom, bo);

        v4f z2b[4], sg[4], dz2[4];
#pragma unroll
        for (int mt = 0; mt < 4; ++mt) {
            z2b[mt] = __builtin_amdgcn_mfma_f32_16x16x32_f16(a2[mt][0].h, bhb[0].h, vb2[mt], 0, 0, 0);
            z2b[mt] = __builtin_amdgcn_mfma_f32_16x16x32_f16(a2[mt][1].h, bhb[1].h, z2b[mt], 0, 0, 0);
            sg[mt] = __builtin_amdgcn_mfma_f32_16x16x32_f16(a2g[mt][0].h, bo[0].h, vzero, 0, 0, 0);
            sg[mt] = __builtin_amdgcn_mfma_f32_16x16x32_f16(a2g[mt][1].h, bo[1].h, sg[mt], 0, 0, 0);
            dz2[mt] = __builtin_amdgcn_mfma_f32_16x16x32_f16(a2d[mt][0].h, bo[0].h, vzero, 0, 0, 0);
            dz2[mt] = __builtin_amdgcn_mfma_f32_16x16x32_f16(a2d[mt][1].h, bo[1].h, dz2[mt], 0, 0, 0);
        }

        // th2b = tanh(z2b). g += om2*sg (w3c pre-folded). th2f = th2b+om2*dz2.
        uint2 ph2[4];
#pragma unroll
        for (int mt = 0; mt < 4; ++mt) {
            v2f th01 = {ftanh_s(z2b[mt][0]), ftanh_s(z2b[mt][1])};
            v2f th23 = {ftanh_s(z2b[mt][2]), ftanh_s(z2b[mt][3])};
            v2f om01 = v2f{1.f, 1.f} - th01 * th01;
            v2f om23 = v2f{1.f, 1.f} - th23 * th23;
            gv += om01 * v2f{sg[mt][0], sg[mt][1]};
            gv += om23 * v2f{sg[mt][2], sg[mt][3]};
            v2f tf01 = om01 * v2f{dz2[mt][0], dz2[mt][1]} + th01;
            v2f tf23 = om23 * v2f{dz2[mt][2], dz2[mt][3]} + th23;
            ph2[mt].x = pk16v(tf01);
            ph2[mt].y = pk16v(tf23);
        }
        FragU bh2[2];
        rename(ph2, bh2);
        v4f d3;
        d3 = __builtin_amdgcn_mfma_f32_16x16x32_f16(a3[0].h, bh2[0].h, vb3, 0, 0, 0);
        d3 = __builtin_amdgcn_mfma_f32_16x16x32_f16(a3[1].h, bh2[1].h, d3, 0, 0, 0);
#pragma unroll
        for (int r = 0; r < 4; ++r) xr[r] = fmaf(dt, d3[r], xr[r]);
    }

    // ============ final bwd at (x_n, t_{n-1}) ============
    {
        FragU bx;
        bx.u[0] = pk16(xr[0], xr[1]);
        bx.u[1] = pk16(xr[2], xr[3]);
        bx.u[2] = pk16(tp, 1.0f); // tp == (n-1)*dt
        bx.u[3] = 0u;
        v4f d1[4];
#pragma unroll
        for (int mt = 0; mt < 4; ++mt)
            d1[mt] = __builtin_amdgcn_mfma_f32_16x16x32_f16(a1[mt].h, bx.h, vzero, 0, 0, 0);
        uint2 phb[4], pom[4];
#pragma unroll
        for (int mt = 0; mt < 4; ++mt) {
            v2f th01 = {ftanh_s(d1[mt][0]), ftanh_s(d1[mt][1])};
            v2f th23 = {ftanh_s(d1[mt][2]), ftanh_s(d1[mt][3])};
            v2f om01 = v2f{1.f, 1.f} - th01 * th01;
            v2f om23 = v2f{1.f, 1.f} - th23 * th23;
            phb[mt].x = pk16v(th01);
            phb[mt].y = pk16v(th23);
            pom[mt].x = pk16v(om01);
            pom[mt].y = pk16v(om23);
        }
        FragU bhb[2], bo[2];
        rename(phb, bhb);
        rename(pom, bo);
        v4f z2b[4], sg[4];
#pragma unroll
        for (int mt = 0; mt < 4; ++mt) {
            z2b[mt] = __builtin_amdgcn_mfma_f32_16x16x32_f16(a2[mt][0].h, bhb[0].h, vb2[mt], 0, 0, 0);
            z2b[mt] = __builtin_amdgcn_mfma_f32_16x16x32_f16(a2[mt][1].h, bhb[1].h, z2b[mt], 0, 0, 0);
            sg[mt] = __builtin_amdgcn_mfma_f32_16x16x32_f16(a2g[mt][0].h, bo[0].h, vzero, 0, 0, 0);
            sg[mt] = __builtin_amdgcn_mfma_f32_16x16x32_f16(a2g[mt][1].h, bo[1].h, sg[mt], 0, 0, 0);
        }
#pragma unroll
        for (int mt = 0; mt < 4; ++mt) {
            v2f th01 = {ftanh_s(z2b[mt][0]), ftanh_s(z2b[mt][1])};
            v2f th23 = {ftanh_s(z2b[mt][2]), ftanh_s(z2b[mt][3])};
            v2f om01 = v2f{1.f, 1.f} - th01 * th01;
            v2f om23 = v2f{1.f, 1.f} - th23 * th23;
            gv += om01 * v2f{sg[mt][0], sg[mt][1]};
            gv += om23 * v2f{sg[mt][2], sg[mt][3]};
        }
    }

    // ---- epilogue ----
    float g = gv.x + gv.y;
    g += __shfl_xor(g, 16);
    g += __shfl_xor(g, 32);
    if (q < 2) {
        float4 st = {xr[0], xr[1], xr[2], xr[3]};
        *(float4*)(out + (size_t)(row0 + c) * 8 + 4 * q) = st;
    }
    if (q == 0) out[(size_t)rows * 8 + row0 + c] = dt * g;
}

extern "C" void kernel_launch(void* const* d_in, const int* in_sizes, int n_in,
                              void* d_out, int out_size, void* d_ws, size_t ws_size,
                              hipStream_t stream) {
    const float* x0 = (const float*)d_in[0];
    const float* W1 = (const float*)d_in[1];
    const float* b1 = (const float*)d_in[2];
    const float* W2 = (const float*)d_in[3];
    const float* b2 = (const float*)d_in[4];
    const float* W3 = (const float*)d_in[5];
    const float* b3 = (const float*)d_in[6];
    const int* ns = (const int*)d_in[7];
    float* out = (float*)d_out;
    const int rows = in_sizes[0] / 8; // 32768

    hipLaunchKernelGGL(cnf_prep, dim3(1), dim3(64), 0, stream, W1, W3);
    hipLaunchKernelGGL(cnf_fused, dim3(rows / 64), dim3(256), 0, stream,
                       x0, W1, b1, W2, b2, W3, b3, ns, out, rows);
}